// Round 3
// baseline (759.847 us; speedup 1.0000x reference)
//
#include <hip/hip_runtime.h>
#include <hip/hip_bf16.h>

typedef __attribute__((ext_vector_type(8))) short short8;
typedef __attribute__((ext_vector_type(4))) float floatx4;
typedef __attribute__((ext_vector_type(4))) int int4v;
typedef __attribute__((ext_vector_type(4))) unsigned int uint4v;

#define MTBL 524288
#define HSTRIDE 72   // fallback kernel only

union U4S8 { uint4v u; short8 s; };

// fp32 -> bf16 round-to-nearest
static __device__ __forceinline__ unsigned int pack2bf(float a, float b) {
    union { float f; unsigned int u; } x, y;
    x.f = a; y.f = b;
    unsigned int lo = (x.u + 0x8000u) >> 16;
    unsigned int hi = (y.u + 0x8000u) & 0xFFFF0000u;
    return lo | hi;
}
static __device__ __forceinline__ short bf1(float a) {
    union { float f; unsigned int u; } x;
    x.f = a;
    return (short)((x.u + 0x8000u) >> 16);
}

// relu + bf16-pack two acc registers into one MFMA B-fragment (8 bf16)
static __device__ __forceinline__ short8 relu_pack(floatx4 a, floatx4 b) {
    U4S8 r;
    r.u[0] = pack2bf(fmaxf(a[0], 0.f), fmaxf(a[1], 0.f));
    r.u[1] = pack2bf(fmaxf(a[2], 0.f), fmaxf(a[3], 0.f));
    r.u[2] = pack2bf(fmaxf(b[0], 0.f), fmaxf(b[1], 0.f));
    r.u[3] = pack2bf(fmaxf(b[2], 0.f), fmaxf(b[3], 0.f));
    return r.s;
}

// ---------------- Kernel T: compress tables fp32 [16*M][2] -> packed bf16 uint ----
__global__ __launch_bounds__(256) void ngp_compress(
    const floatx4* __restrict__ tab4, unsigned int* __restrict__ tblC)
{
    const int t = blockIdx.x * 256 + threadIdx.x;   // handles entries 4t..4t+3
    floatx4 a = __builtin_nontemporal_load(tab4 + (size_t)2 * t);
    floatx4 b = __builtin_nontemporal_load(tab4 + (size_t)2 * t + 1);
    uint4v w;
    w[0] = pack2bf(a[0], a[1]);
    w[1] = pack2bf(a[2], a[3]);
    w[2] = pack2bf(b[0], b[1]);
    w[3] = pack2bf(b[2], b[3]);
    __builtin_nontemporal_store(w, (uint4v*)(tblC + (size_t)4 * t));
}

// 4 random dword gathers from the bf16-packed table (heads 4q..4q+3)
static __device__ __forceinline__ uint4v gather4(
    const unsigned int* __restrict__ tq, int4v iv)
{
    uint4v g;
    g[0] = tq[iv[0]];
    g[1] = tq[MTBL + iv[1]];
    g[2] = tq[(size_t)2 * MTBL + iv[2]];
    g[3] = tq[(size_t)3 * MTBL + iv[3]];
    return g;
}

// one full MLP chain for a 16-point tile, lane-local transitions (see layout
// comment in ngp_fused2: permuted A-columns make B-frag = relu_pack(own acc))
static __device__ __forceinline__ floatx4 mlp_chain(
    uint4v cur,
    const short8 (&A1)[4], const short8 (&A2)[4][2], const short8 (&A3)[4][2],
    const short8 (&A4)[2],
    const floatx4 (&C1)[4], const floatx4 (&C2)[4], const floatx4 (&C3)[4],
    floatx4 C4)
{
    U4S8 bx; bx.u = cur;
    const short8 Bx = bx.s;

    floatx4 h[4];
#pragma unroll
    for (int t = 0; t < 4; ++t)
        h[t] = __builtin_amdgcn_mfma_f32_16x16x32_bf16(A1[t], Bx, C1[t], 0, 0, 0);
    short8 B0 = relu_pack(h[0], h[1]);
    short8 B1 = relu_pack(h[2], h[3]);

#pragma unroll
    for (int t = 0; t < 4; ++t) {
        h[t] = __builtin_amdgcn_mfma_f32_16x16x32_bf16(A2[t][0], B0, C2[t], 0, 0, 0);
        h[t] = __builtin_amdgcn_mfma_f32_16x16x32_bf16(A2[t][1], B1, h[t], 0, 0, 0);
    }
    B0 = relu_pack(h[0], h[1]);
    B1 = relu_pack(h[2], h[3]);

#pragma unroll
    for (int t = 0; t < 4; ++t) {
        h[t] = __builtin_amdgcn_mfma_f32_16x16x32_bf16(A3[t][0], B0, C3[t], 0, 0, 0);
        h[t] = __builtin_amdgcn_mfma_f32_16x16x32_bf16(A3[t][1], B1, h[t], 0, 0, 0);
    }
    B0 = relu_pack(h[0], h[1]);
    B1 = relu_pack(h[2], h[3]);

    floatx4 o;
    o = __builtin_amdgcn_mfma_f32_16x16x32_bf16(A4[0], B0, C4, 0, 0, 0);
    o = __builtin_amdgcn_mfma_f32_16x16x32_bf16(A4[1], B1, o, 0, 0, 0);
    return o;
}

// ---------------- Kernel F: fused gather + MFMA MLP ----------------
// Drops idxT/xU round-trips (512 MB of HBM) and two kernel launches.
// Gathers hit the 32 MB bf16 table (L3-resident; ~12% L2).  Software pipeline:
// gathers for iteration k+1 issue before computing iteration k (~1700 cy of
// MLP chain covers L3 latency); idx loads run two iterations ahead.
// 2 independent tiles per iteration double MFMA issue density (chain was
// latency-bound at MfmaUtil 12.6%).
// Layout trick (R1): A-fragment t covers permuted output columns
//   c_t(p) = 32*(t>>1) + 4*(t&1) + 8*(p>>2) + (p&3)
// so lane (q,m) holds h[32*(t>>1)+4*(t&1)+8q+r] in acc[t][r] and the next
// layer's B-fragment is relu_pack of the SAME lane's accumulators.
__global__ __launch_bounds__(256, 2) void ngp_fused2(
    const int* __restrict__ idx,
    const unsigned int* __restrict__ tblC,
    const float* __restrict__ W1, const float* __restrict__ b1,
    const float* __restrict__ W2, const float* __restrict__ b2,
    const float* __restrict__ W3, const float* __restrict__ b3,
    const float* __restrict__ W4, const float* __restrict__ b4,
    float* __restrict__ out, int tiles_per_wave)
{
    __shared__ float sW[10632];  // W1@0 W2@2048 W3@6144 W4@10240 b@10432

    const int tid = threadIdx.x;
    for (int i = tid; i < 2048; i += 256) sW[i] = W1[i];
    for (int i = tid; i < 4096; i += 256) sW[2048 + i] = W2[i];
    for (int i = tid; i < 4096; i += 256) sW[6144 + i] = W3[i];
    if (tid < 192) sW[10240 + tid] = W4[tid];
    if (tid < 64)       sW[10432 + tid] = b1[tid];
    else if (tid < 128) sW[10432 + tid] = b2[tid - 64];
    else if (tid < 192) sW[10432 + tid] = b3[tid - 128];
    else if (tid < 195) sW[10432 + tid] = b4[tid - 192];
    __syncthreads();

    const int wave = tid >> 6;
    const int lane = tid & 63;
    const int q = lane >> 4;
    const int m = lane & 15;

    int ct[4];
#pragma unroll
    for (int t = 0; t < 4; ++t)
        ct[t] = 32 * (t >> 1) + 4 * (t & 1) + 8 * (m >> 2) + (m & 3);

    short8 A1[4], A2[4][2], A3[4][2], A4[2];
    floatx4 C1[4], C2[4], C3[4], C4;

#pragma unroll
    for (int t = 0; t < 4; ++t) {
        short8 a;
#pragma unroll
        for (int j = 0; j < 8; ++j)
            a[j] = bf1(sW[(q * 8 + j) * 64 + ct[t]]);
        A1[t] = a;
    }
#pragma unroll
    for (int t = 0; t < 4; ++t)
#pragma unroll
        for (int c = 0; c < 2; ++c) {
            short8 a2, a3;
#pragma unroll
            for (int j = 0; j < 8; ++j) {
                a2[j] = bf1(sW[2048 + (c * 32 + q * 8 + j) * 64 + ct[t]]);
                a3[j] = bf1(sW[6144 + (c * 32 + q * 8 + j) * 64 + ct[t]]);
            }
            A2[t][c] = a2;
            A3[t][c] = a3;
        }
#pragma unroll
    for (int c = 0; c < 2; ++c) {
        short8 a;
#pragma unroll
        for (int j = 0; j < 8; ++j)
            a[j] = (m < 3) ? bf1(sW[10240 + (c * 32 + q * 8 + j) * 3 + m]) : (short)0;
        A4[c] = a;
    }
#pragma unroll
    for (int t = 0; t < 4; ++t) {
        const int bi = 32 * (t >> 1) + 4 * (t & 1) + 8 * q;
#pragma unroll
        for (int r = 0; r < 4; ++r) {
            C1[t][r] = sW[10432 + bi + r];
            C2[t][r] = sW[10432 + 64 + bi + r];
            C3[t][r] = sW[10432 + 128 + bi + r];
        }
    }
#pragma unroll
    for (int r = 0; r < 4; ++r)
        C4[r] = (q == 0 && r < 3) ? sW[10432 + 192 + r] : 0.0f;

    const int gw = blockIdx.x * 4 + wave;
    const int tile0 = gw * tiles_per_wave;
    const int iters = tiles_per_wave >> 1;    // 2 tiles per iteration

    const int4v* __restrict__ idx4 = (const int4v*)idx;
    const unsigned int* __restrict__ tq = tblC + (size_t)(q * 4) * MTBL;

    // idx fetch for tile t: lane (q,m) -> indices of heads 4q..4q+3 of point t*16+m
    #define IDXLD(t) __builtin_nontemporal_load(idx4 + (size_t)((t) * 16 + m) * 4 + q)

    // ---- pipeline prologue ----
    int4v ivA = IDXLD(tile0);
    int4v ivB = IDXLD(tile0 + 1);
    uint4v curA = gather4(tq, ivA);
    uint4v curB = gather4(tq, ivB);
    if (iters > 1) {
        ivA = IDXLD(tile0 + 2);
        ivB = IDXLD(tile0 + 3);
    }

    for (int k = 0; k < iters; ++k) {
        const int pbaseA = (tile0 + 2 * k) * 16;
        const bool more  = (k + 1) < iters;
        const bool more2 = (k + 2) < iters;

        // issue gathers for iteration k+1 (indices already resident)
        uint4v nxtA = curA, nxtB = curB;
        if (more) {
            nxtA = gather4(tq, ivA);
            nxtB = gather4(tq, ivB);
        }
        // issue idx loads for iteration k+2
        if (more2) {
            ivA = IDXLD(tile0 + 2 * k + 4);
            ivB = IDXLD(tile0 + 2 * k + 5);
        }

        // two independent MLP chains (interleaved by the scheduler)
        floatx4 oA = mlp_chain(curA, A1, A2, A3, A4, C1, C2, C3, C4);
        floatx4 oB = mlp_chain(curB, A1, A2, A3, A4, C1, C2, C3, C4);

        if (q == 0) {
            const int pA = pbaseA + m;
            __builtin_nontemporal_store(oA[0], out + pA * 3 + 0);
            __builtin_nontemporal_store(oA[1], out + pA * 3 + 1);
            __builtin_nontemporal_store(oA[2], out + pA * 3 + 2);
            const int pB = pA + 16;
            __builtin_nontemporal_store(oB[0], out + pB * 3 + 0);
            __builtin_nontemporal_store(oB[1], out + pB * 3 + 1);
            __builtin_nontemporal_store(oB[2], out + pB * 3 + 2);
        }

        curA = nxtA;
        curB = nxtB;
    }
    #undef IDXLD
}

// ---------------- Fallback: fused kernel without workspace ----------------
__global__ __launch_bounds__(256, 2) void ngp_fused(
    const int* __restrict__ idx,
    const float* __restrict__ tables,
    const float* __restrict__ W1, const float* __restrict__ b1,
    const float* __restrict__ W2, const float* __restrict__ b2,
    const float* __restrict__ W3, const float* __restrict__ b3,
    const float* __restrict__ W4, const float* __restrict__ b4,
    float* __restrict__ out, int tiles_per_wave)
{
    __shared__ float sW1[2048];
    __shared__ float sW2[4096];
    __shared__ float sW3[4096];
    __shared__ float sW4[192];
    __shared__ float sB[200];
    __shared__ __hip_bfloat16 sH[4][16 * HSTRIDE];

    const int tid = threadIdx.x;
    for (int i = tid; i < 2048; i += 256) sW1[i] = W1[i];
    for (int i = tid; i < 4096; i += 256) sW2[i] = W2[i];
    for (int i = tid; i < 4096; i += 256) sW3[i] = W3[i];
    if (tid < 192) sW4[tid] = W4[tid];
    if (tid < 64)       sB[tid] = b1[tid];
    else if (tid < 128) sB[tid] = b2[tid - 64];
    else if (tid < 192) sB[tid] = b3[tid - 128];
    else if (tid < 195) sB[tid] = b4[tid - 192];
    __syncthreads();

    const int wave = tid >> 6;
    const int lane = tid & 63;
    const int q = lane >> 4;
    const int m = lane & 15;

    short8 A1[4], A2[4][2], A3[4][2], A4[2];
#pragma unroll
    for (int t = 0; t < 4; ++t) {
        short8 a;
#pragma unroll
        for (int j = 0; j < 8; ++j)
            a[j] = bf1(sW1[(q * 8 + j) * 64 + t * 16 + m]);
        A1[t] = a;
    }
#pragma unroll
    for (int t = 0; t < 4; ++t)
#pragma unroll
        for (int c = 0; c < 2; ++c) {
            short8 a, a3;
#pragma unroll
            for (int j = 0; j < 8; ++j) {
                a[j]  = bf1(sW2[(c * 32 + q * 8 + j) * 64 + t * 16 + m]);
                a3[j] = bf1(sW3[(c * 32 + q * 8 + j) * 64 + t * 16 + m]);
            }
            A2[t][c] = a;
            A3[t][c] = a3;
        }
#pragma unroll
    for (int c = 0; c < 2; ++c) {
        short8 a;
#pragma unroll
        for (int j = 0; j < 8; ++j)
            a[j] = (m < 3) ? bf1(sW4[(c * 32 + q * 8 + j) * 3 + m]) : (short)0;
        A4[c] = a;
    }

    floatx4 C1[4], C2[4], C3[4], C4;
#pragma unroll
    for (int t = 0; t < 4; ++t)
#pragma unroll
        for (int r = 0; r < 4; ++r) {
            C1[t][r] = sB[t * 16 + q * 4 + r];
            C2[t][r] = sB[64 + t * 16 + q * 4 + r];
            C3[t][r] = sB[128 + t * 16 + q * 4 + r];
        }
#pragma unroll
    for (int r = 0; r < 4; ++r)
        C4[r] = (q == 0 && r < 3) ? sB[192 + r] : 0.0f;

    __hip_bfloat16* hrow = &sH[wave][m * HSTRIDE];
    const int4*   idx4 = (const int4*)idx;
    const float2* tbl  = (const float2*)tables;

    const int gw = blockIdx.x * 4 + wave;
    const int tile0 = gw * tiles_per_wave;

    int4 iv = idx4[(tile0 * 16 + m) * 4 + q];
    float2 g0 = tbl[(q * 4 + 0) * MTBL + iv.x];
    float2 g1 = tbl[(q * 4 + 1) * MTBL + iv.y];
    float2 g2 = tbl[(q * 4 + 2) * MTBL + iv.z];
    float2 g3 = tbl[(q * 4 + 3) * MTBL + iv.w];

    for (int it = 0; it < tiles_per_wave; ++it) {
        const int pbase = (tile0 + it) * 16;
        const bool more = (it + 1) < tiles_per_wave;

        short8 Bx;
        {
            unsigned int p0 = pack2bf(g0.x, g0.y);
            unsigned int p1 = pack2bf(g1.x, g1.y);
            unsigned int p2 = pack2bf(g2.x, g2.y);
            unsigned int p3 = pack2bf(g3.x, g3.y);
            Bx[0] = (short)(p0 & 0xFFFF); Bx[1] = (short)(p0 >> 16);
            Bx[2] = (short)(p1 & 0xFFFF); Bx[3] = (short)(p1 >> 16);
            Bx[4] = (short)(p2 & 0xFFFF); Bx[5] = (short)(p2 >> 16);
            Bx[6] = (short)(p3 & 0xFFFF); Bx[7] = (short)(p3 >> 16);
        }

        int4 ivn;
        if (more) ivn = idx4[((pbase + 16) + m) * 4 + q];

        floatx4 acc[4];
#pragma unroll
        for (int t = 0; t < 4; ++t)
            acc[t] = __builtin_amdgcn_mfma_f32_16x16x32_bf16(A1[t], Bx, C1[t], 0, 0, 0);

#pragma unroll
        for (int t = 0; t < 4; ++t) {
            uint2 pk;
            pk.x = pack2bf(fmaxf(acc[t][0], 0.f), fmaxf(acc[t][1], 0.f));
            pk.y = pack2bf(fmaxf(acc[t][2], 0.f), fmaxf(acc[t][3], 0.f));
            *(uint2*)(hrow + t * 16 + q * 4) = pk;
        }
        short8 Bh0 = *(const short8*)(hrow + q * 8);
        short8 Bh1 = *(const short8*)(hrow + 32 + q * 8);

#pragma unroll
        for (int t = 0; t < 4; ++t) {
            acc[t] = __builtin_amdgcn_mfma_f32_16x16x32_bf16(A2[t][0], Bh0, C2[t], 0, 0, 0);
            acc[t] = __builtin_amdgcn_mfma_f32_16x16x32_bf16(A2[t][1], Bh1, acc[t], 0, 0, 0);
        }

        if (more) {
            g0 = tbl[(q * 4 + 0) * MTBL + ivn.x];
            g1 = tbl[(q * 4 + 1) * MTBL + ivn.y];
            g2 = tbl[(q * 4 + 2) * MTBL + ivn.z];
            g3 = tbl[(q * 4 + 3) * MTBL + ivn.w];
        }

#pragma unroll
        for (int t = 0; t < 4; ++t) {
            uint2 pk;
            pk.x = pack2bf(fmaxf(acc[t][0], 0.f), fmaxf(acc[t][1], 0.f));
            pk.y = pack2bf(fmaxf(acc[t][2], 0.f), fmaxf(acc[t][3], 0.f));
            *(uint2*)(hrow + t * 16 + q * 4) = pk;
        }
        Bh0 = *(const short8*)(hrow + q * 8);
        Bh1 = *(const short8*)(hrow + 32 + q * 8);

#pragma unroll
        for (int t = 0; t < 4; ++t) {
            acc[t] = __builtin_amdgcn_mfma_f32_16x16x32_bf16(A3[t][0], Bh0, C3[t], 0, 0, 0);
            acc[t] = __builtin_amdgcn_mfma_f32_16x16x32_bf16(A3[t][1], Bh1, acc[t], 0, 0, 0);
        }

#pragma unroll
        for (int t = 0; t < 4; ++t) {
            uint2 pk;
            pk.x = pack2bf(fmaxf(acc[t][0], 0.f), fmaxf(acc[t][1], 0.f));
            pk.y = pack2bf(fmaxf(acc[t][2], 0.f), fmaxf(acc[t][3], 0.f));
            *(uint2*)(hrow + t * 16 + q * 4) = pk;
        }
        Bh0 = *(const short8*)(hrow + q * 8);
        Bh1 = *(const short8*)(hrow + 32 + q * 8);

        floatx4 o;
        o = __builtin_amdgcn_mfma_f32_16x16x32_bf16(A4[0], Bh0, C4, 0, 0, 0);
        o = __builtin_amdgcn_mfma_f32_16x16x32_bf16(A4[1], Bh1, o, 0, 0, 0);

        if (q == 0) {
            const int pn = pbase + m;
            out[pn * 3 + 0] = o[0];
            out[pn * 3 + 1] = o[1];
            out[pn * 3 + 2] = o[2];
        }
    }
}

extern "C" void kernel_launch(void* const* d_in, const int* in_sizes, int n_in,
                              void* d_out, int out_size, void* d_ws, size_t ws_size,
                              hipStream_t stream) {
    const int*   idx    = (const int*)d_in[0];
    const float* tables = (const float*)d_in[1];
    const float* W1 = (const float*)d_in[2];
    const float* b1 = (const float*)d_in[3];
    const float* W2 = (const float*)d_in[4];
    const float* b2 = (const float*)d_in[5];
    const float* W3 = (const float*)d_in[6];
    const float* b3 = (const float*)d_in[7];
    const float* W4 = (const float*)d_in[8];
    const float* b4 = (const float*)d_in[9];
    float* out = (float*)d_out;

    const int N = in_sizes[0] / 16;            // points (2,097,152)
    const int total_tiles = N / 16;
    const size_t tblC_bytes = (size_t)16 * MTBL * 4;        // 32 MiB

    if (ws_size >= tblC_bytes) {
        unsigned int* tblC = (unsigned int*)d_ws;

        // T: compress tables to packed bf16 (16*M entries, 4 per thread)
        ngp_compress<<<(16 * MTBL) / 1024, 256, 0, stream>>>(
            (const floatx4*)tables, tblC);
        // F: fused gather + MLP
        const int blocks = 2048;
        const int tiles_per_wave = total_tiles / (blocks * 4);   // 16
        ngp_fused2<<<blocks, 256, 0, stream>>>(idx, tblC, W1, b1, W2, b2,
                                               W3, b3, W4, b4, out,
                                               tiles_per_wave);
    } else {
        const int blocks = 2048;
        const int tiles_per_wave = total_tiles / (blocks * 4);
        ngp_fused<<<blocks, 256, 0, stream>>>(idx, tables, W1, b1, W2, b2, W3, b3,
                                              W4, b4, out, tiles_per_wave);
    }
}

// Round 4
// 685.761 us; speedup vs baseline: 1.1080x; 1.1080x over previous
//
#include <hip/hip_runtime.h>
#include <hip/hip_bf16.h>

typedef __attribute__((ext_vector_type(8))) short short8;
typedef __attribute__((ext_vector_type(4))) float floatx4;
typedef __attribute__((ext_vector_type(4))) int int4v;
typedef __attribute__((ext_vector_type(4))) unsigned int uint4v;

#define MTBL 524288
#define HSTRIDE 72   // fallback kernel only

union U4S8 { uint4v u; short8 s; };

// fp32 -> bf16 round-to-nearest
static __device__ __forceinline__ unsigned int pack2bf(float a, float b) {
    union { float f; unsigned int u; } x, y;
    x.f = a; y.f = b;
    unsigned int lo = (x.u + 0x8000u) >> 16;
    unsigned int hi = (y.u + 0x8000u) & 0xFFFF0000u;
    return lo | hi;
}
static __device__ __forceinline__ short bf1(float a) {
    union { float f; unsigned int u; } x;
    x.f = a;
    return (short)((x.u + 0x8000u) >> 16);
}

// relu + bf16-pack two acc registers into one MFMA B-fragment (8 bf16)
static __device__ __forceinline__ short8 relu_pack(floatx4 a, floatx4 b) {
    U4S8 r;
    r.u[0] = pack2bf(fmaxf(a[0], 0.f), fmaxf(a[1], 0.f));
    r.u[1] = pack2bf(fmaxf(a[2], 0.f), fmaxf(a[3], 0.f));
    r.u[2] = pack2bf(fmaxf(b[0], 0.f), fmaxf(b[1], 0.f));
    r.u[3] = pack2bf(fmaxf(b[2], 0.f), fmaxf(b[3], 0.f));
    return r.s;
}

// one full MLP chain for a 16-point tile, lane-local transitions.
// Layout trick (R1): A-fragment t covers permuted output columns
//   c_t(p) = 32*(t>>1) + 4*(t&1) + 8*(p>>2) + (p&3)
// so lane (q,m) holds h[32*(t>>1)+4*(t&1)+8q+r] in acc[t][r] and the next
// layer's B-fragment is relu_pack of the SAME lane's accumulators.
static __device__ __forceinline__ floatx4 mlp_chain(
    uint4v cur,
    const short8 (&A1)[4], const short8 (&A2)[4][2], const short8 (&A3)[4][2],
    const short8 (&A4)[2],
    const floatx4 (&C1)[4], const floatx4 (&C2)[4], const floatx4 (&C3)[4],
    floatx4 C4)
{
    U4S8 bx; bx.u = cur;
    const short8 Bx = bx.s;

    floatx4 h[4];
#pragma unroll
    for (int t = 0; t < 4; ++t)
        h[t] = __builtin_amdgcn_mfma_f32_16x16x32_bf16(A1[t], Bx, C1[t], 0, 0, 0);
    short8 B0 = relu_pack(h[0], h[1]);
    short8 B1 = relu_pack(h[2], h[3]);

#pragma unroll
    for (int t = 0; t < 4; ++t) {
        h[t] = __builtin_amdgcn_mfma_f32_16x16x32_bf16(A2[t][0], B0, C2[t], 0, 0, 0);
        h[t] = __builtin_amdgcn_mfma_f32_16x16x32_bf16(A2[t][1], B1, h[t], 0, 0, 0);
    }
    B0 = relu_pack(h[0], h[1]);
    B1 = relu_pack(h[2], h[3]);

#pragma unroll
    for (int t = 0; t < 4; ++t) {
        h[t] = __builtin_amdgcn_mfma_f32_16x16x32_bf16(A3[t][0], B0, C3[t], 0, 0, 0);
        h[t] = __builtin_amdgcn_mfma_f32_16x16x32_bf16(A3[t][1], B1, h[t], 0, 0, 0);
    }
    B0 = relu_pack(h[0], h[1]);
    B1 = relu_pack(h[2], h[3]);

    floatx4 o;
    o = __builtin_amdgcn_mfma_f32_16x16x32_bf16(A4[0], B0, C4, 0, 0, 0);
    o = __builtin_amdgcn_mfma_f32_16x16x32_bf16(A4[1], B1, o, 0, 0, 0);
    return o;
}

// ---------------- Kernel P: fused prep ----------------
// blocks [0, N/1024):           transpose idx [N][16] -> idxT [16][N]
// blocks [N/1024, +16M/1024):   compress tables fp32 [16*M][2] -> packed bf16
__global__ __launch_bounds__(256) void ngp_prep(
    const int* __restrict__ idx, int* __restrict__ idxT,
    const floatx4* __restrict__ tab4, unsigned int* __restrict__ tblC, int N)
{
    const int tblocks = N >> 10;
    if ((int)blockIdx.x < tblocks) {
        const int t  = blockIdx.x * 256 + threadIdx.x;
        const int p0 = t * 4;
        const int4v* rows = (const int4v*)idx;
        int4v r[4][4];
#pragma unroll
        for (int p = 0; p < 4; ++p)
#pragma unroll
            for (int c = 0; c < 4; ++c)
                r[p][c] = __builtin_nontemporal_load(rows + (size_t)(p0 + p) * 4 + c);
#pragma unroll
        for (int c = 0; c < 4; ++c)
#pragma unroll
            for (int k = 0; k < 4; ++k) {
                const int h = c * 4 + k;
                int4v w;
                w[0] = r[0][c][k]; w[1] = r[1][c][k]; w[2] = r[2][c][k]; w[3] = r[3][c][k];
                __builtin_nontemporal_store(w, (int4v*)(idxT + (size_t)h * N + p0));
            }
    } else {
        const int t = (blockIdx.x - tblocks) * 256 + threadIdx.x;
        floatx4 a = __builtin_nontemporal_load(tab4 + (size_t)2 * t);
        floatx4 b = __builtin_nontemporal_load(tab4 + (size_t)2 * t + 1);
        uint4v w;
        w[0] = pack2bf(a[0], a[1]);
        w[1] = pack2bf(a[2], a[3]);
        w[2] = pack2bf(b[0], b[1]);
        w[3] = pack2bf(b[2], b[3]);
        __builtin_nontemporal_store(w, (uint4v*)(tblC + (size_t)4 * t));
    }
}

// ---------------- Kernel B: one-head-per-XCD gather phase ----------------
// head = (blk&7)*2 + phase; per-XCD live table slice = 2 MiB (bf16-packed)
// < 4 MiB L2 -> gathers are L2 hits.  L2-hit latency (~200 cy) x outstanding
// misses bounds throughput, so keep 16 gathers in flight per thread.
__global__ __launch_bounds__(256) void ngp_gather_ph(
    const int* __restrict__ idxT, const unsigned int* __restrict__ tblC,
    unsigned int* __restrict__ xU, int N, int phase, int iters)
{
    const int h    = ((blockIdx.x & 7) << 1) | phase;
    const int slot = blockIdx.x >> 3;                 // 0..255
    const int* __restrict__ ih = idxT + (size_t)h * N;
    const unsigned int* __restrict__ th = tblC + (size_t)h * MTBL;
    unsigned int* __restrict__ xh = xU + (size_t)h * N;

    int p = slot * (N >> 8) + (threadIdx.x << 4);     // 16 points per thread per iter
    int4v iv[4];
#pragma unroll
    for (int c = 0; c < 4; ++c)
        iv[c] = __builtin_nontemporal_load((const int4v*)(ih + p + 4 * c));
    for (int it = 0; it < iters; ++it) {
        int4v nv[4];
#pragma unroll
        for (int c = 0; c < 4; ++c) nv[c] = iv[c];
        if (it + 1 < iters) {
#pragma unroll
            for (int c = 0; c < 4; ++c)
                nv[c] = __builtin_nontemporal_load((const int4v*)(ih + p + 4096 + 4 * c));
        }
        uint4v w[4];
#pragma unroll
        for (int c = 0; c < 4; ++c) {
            w[c][0] = th[iv[c][0]];
            w[c][1] = th[iv[c][1]];
            w[c][2] = th[iv[c][2]];
            w[c][3] = th[iv[c][3]];
        }
#pragma unroll
        for (int c = 0; c < 4; ++c)
            __builtin_nontemporal_store(w[c], (uint4v*)(xh + p + 4 * c));
#pragma unroll
        for (int c = 0; c < 4; ++c) iv[c] = nv[c];
        p += 4096;
    }
}

// ---------------- Kernel C: MFMA MLP on contiguous xU ----------------
// Lane-local layer transitions (no LDS in loop), 2 independent tiles per
// iteration (chain was latency-bound at MfmaUtil 12.6%), two-stage 24 KB
// weight staging (was 42 KB) for higher occupancy.
// launch_bounds (256,2): (256,4) forced VGPR=64 and spilled (R0 post-mortem).
__global__ __launch_bounds__(256, 2) void ngp_mlp(
    const unsigned int* __restrict__ xU,
    const float* __restrict__ W1, const float* __restrict__ b1,
    const float* __restrict__ W2, const float* __restrict__ b2,
    const float* __restrict__ W3, const float* __restrict__ b3,
    const float* __restrict__ W4, const float* __restrict__ b4,
    float* __restrict__ out, int N, int tiles_per_wave)
{
    __shared__ float sW[6144];   // 24 KB, reused across 2 staging stages

    const int tid  = threadIdx.x;
    const int wave = tid >> 6;
    const int lane = tid & 63;
    const int q = lane >> 4;
    const int m = lane & 15;

    int ct[4];
#pragma unroll
    for (int t = 0; t < 4; ++t)
        ct[t] = 32 * (t >> 1) + 4 * (t & 1) + 8 * (m >> 2) + (m & 3);

    short8 A1[4], A2[4][2], A3[4][2], A4[2];
    floatx4 C1[4], C2[4], C3[4], C4;

    // ---- stage A: W1 (2048) + W2 (4096) ----
    for (int i = tid; i < 2048; i += 256) sW[i] = W1[i];
    for (int i = tid; i < 4096; i += 256) sW[2048 + i] = W2[i];
    __syncthreads();
#pragma unroll
    for (int t = 0; t < 4; ++t) {
        short8 a;
#pragma unroll
        for (int j = 0; j < 8; ++j)
            a[j] = bf1(sW[(q * 8 + j) * 64 + ct[t]]);
        A1[t] = a;
    }
#pragma unroll
    for (int t = 0; t < 4; ++t)
#pragma unroll
        for (int c = 0; c < 2; ++c) {
            short8 a;
#pragma unroll
            for (int j = 0; j < 8; ++j)
                a[j] = bf1(sW[2048 + (c * 32 + q * 8 + j) * 64 + ct[t]]);
            A2[t][c] = a;
        }
    __syncthreads();

    // ---- stage B: W3 (4096) + W4 (192) + biases (195) ----
    for (int i = tid; i < 4096; i += 256) sW[i] = W3[i];
    if (tid < 192) sW[4096 + tid] = W4[tid];
    if (tid < 64)       sW[4288 + tid] = b1[tid];
    else if (tid < 128) sW[4288 + tid] = b2[tid - 64];
    else if (tid < 192) sW[4288 + tid] = b3[tid - 128];
    else if (tid < 195) sW[4288 + tid] = b4[tid - 192];
    __syncthreads();
#pragma unroll
    for (int t = 0; t < 4; ++t)
#pragma unroll
        for (int c = 0; c < 2; ++c) {
            short8 a;
#pragma unroll
            for (int j = 0; j < 8; ++j)
                a[j] = bf1(sW[(c * 32 + q * 8 + j) * 64 + ct[t]]);
            A3[t][c] = a;
        }
#pragma unroll
    for (int c = 0; c < 2; ++c) {
        short8 a;
#pragma unroll
        for (int j = 0; j < 8; ++j)
            a[j] = (m < 3) ? bf1(sW[4096 + (c * 32 + q * 8 + j) * 3 + m]) : (short)0;
        A4[c] = a;
    }
#pragma unroll
    for (int t = 0; t < 4; ++t) {
        const int bi = 32 * (t >> 1) + 4 * (t & 1) + 8 * q;   // permuted bias base
#pragma unroll
        for (int r = 0; r < 4; ++r) {
            C1[t][r] = sW[4288 + bi + r];
            C2[t][r] = sW[4288 + 64 + bi + r];
            C3[t][r] = sW[4288 + 128 + bi + r];
        }
    }
#pragma unroll
    for (int r = 0; r < 4; ++r)
        C4[r] = (q == 0 && r < 3) ? sW[4288 + 192 + r] : 0.0f;

    const int gw = blockIdx.x * 4 + wave;
    const int tile0 = gw * tiles_per_wave;
    const int iters = tiles_per_wave >> 1;    // 2 tiles per iteration

    const unsigned int* xr = xU + (size_t)(q * 4) * N + m;

    #define XLD(tile, c) xr[(size_t)(c) * N + (tile) * 16]

    uint4v curA, curB;
    {
        curA[0] = XLD(tile0, 0);     curA[1] = XLD(tile0, 1);
        curA[2] = XLD(tile0, 2);     curA[3] = XLD(tile0, 3);
        curB[0] = XLD(tile0 + 1, 0); curB[1] = XLD(tile0 + 1, 1);
        curB[2] = XLD(tile0 + 1, 2); curB[3] = XLD(tile0 + 1, 3);
    }

    for (int k = 0; k < iters; ++k) {
        const int pbaseA = (tile0 + 2 * k) * 16;
        const bool more = (k + 1) < iters;

        uint4v nxtA = curA, nxtB = curB;
        if (more) {
            const int tn = tile0 + 2 * k + 2;
            nxtA[0] = XLD(tn, 0);     nxtA[1] = XLD(tn, 1);
            nxtA[2] = XLD(tn, 2);     nxtA[3] = XLD(tn, 3);
            nxtB[0] = XLD(tn + 1, 0); nxtB[1] = XLD(tn + 1, 1);
            nxtB[2] = XLD(tn + 1, 2); nxtB[3] = XLD(tn + 1, 3);
        }

        floatx4 oA = mlp_chain(curA, A1, A2, A3, A4, C1, C2, C3, C4);
        floatx4 oB = mlp_chain(curB, A1, A2, A3, A4, C1, C2, C3, C4);

        if (q == 0) {
            const int pA = pbaseA + m;
            __builtin_nontemporal_store(oA[0], out + pA * 3 + 0);
            __builtin_nontemporal_store(oA[1], out + pA * 3 + 1);
            __builtin_nontemporal_store(oA[2], out + pA * 3 + 2);
            const int pB = pA + 16;
            __builtin_nontemporal_store(oB[0], out + pB * 3 + 0);
            __builtin_nontemporal_store(oB[1], out + pB * 3 + 1);
            __builtin_nontemporal_store(oB[2], out + pB * 3 + 2);
        }

        curA = nxtA;
        curB = nxtB;
    }
    #undef XLD
}

// ---------------- Fallback: fused kernel without workspace ----------------
__global__ __launch_bounds__(256, 2) void ngp_fused(
    const int* __restrict__ idx,
    const float* __restrict__ tables,
    const float* __restrict__ W1, const float* __restrict__ b1,
    const float* __restrict__ W2, const float* __restrict__ b2,
    const float* __restrict__ W3, const float* __restrict__ b3,
    const float* __restrict__ W4, const float* __restrict__ b4,
    float* __restrict__ out, int tiles_per_wave)
{
    __shared__ float sW1[2048];
    __shared__ float sW2[4096];
    __shared__ float sW3[4096];
    __shared__ float sW4[192];
    __shared__ float sB[200];
    __shared__ __hip_bfloat16 sH[4][16 * HSTRIDE];

    const int tid = threadIdx.x;
    for (int i = tid; i < 2048; i += 256) sW1[i] = W1[i];
    for (int i = tid; i < 4096; i += 256) sW2[i] = W2[i];
    for (int i = tid; i < 4096; i += 256) sW3[i] = W3[i];
    if (tid < 192) sW4[tid] = W4[tid];
    if (tid < 64)       sB[tid] = b1[tid];
    else if (tid < 128) sB[tid] = b2[tid - 64];
    else if (tid < 192) sB[tid] = b3[tid - 128];
    else if (tid < 195) sB[tid] = b4[tid - 192];
    __syncthreads();

    const int wave = tid >> 6;
    const int lane = tid & 63;
    const int q = lane >> 4;
    const int m = lane & 15;

    short8 A1[4], A2[4][2], A3[4][2], A4[2];
#pragma unroll
    for (int t = 0; t < 4; ++t) {
        short8 a;
#pragma unroll
        for (int j = 0; j < 8; ++j)
            a[j] = bf1(sW1[(q * 8 + j) * 64 + t * 16 + m]);
        A1[t] = a;
    }
#pragma unroll
    for (int t = 0; t < 4; ++t)
#pragma unroll
        for (int c = 0; c < 2; ++c) {
            short8 a, a3;
#pragma unroll
            for (int j = 0; j < 8; ++j) {
                a[j]  = bf1(sW2[(c * 32 + q * 8 + j) * 64 + t * 16 + m]);
                a3[j] = bf1(sW3[(c * 32 + q * 8 + j) * 64 + t * 16 + m]);
            }
            A2[t][c] = a;
            A3[t][c] = a3;
        }
#pragma unroll
    for (int c = 0; c < 2; ++c) {
        short8 a;
#pragma unroll
        for (int j = 0; j < 8; ++j)
            a[j] = (m < 3) ? bf1(sW4[(c * 32 + q * 8 + j) * 3 + m]) : (short)0;
        A4[c] = a;
    }

    floatx4 C1[4], C2[4], C3[4], C4;
#pragma unroll
    for (int t = 0; t < 4; ++t)
#pragma unroll
        for (int r = 0; r < 4; ++r) {
            C1[t][r] = sB[t * 16 + q * 4 + r];
            C2[t][r] = sB[64 + t * 16 + q * 4 + r];
            C3[t][r] = sB[128 + t * 16 + q * 4 + r];
        }
#pragma unroll
    for (int r = 0; r < 4; ++r)
        C4[r] = (q == 0 && r < 3) ? sB[192 + r] : 0.0f;

    __hip_bfloat16* hrow = &sH[wave][m * HSTRIDE];
    const int4*   idx4 = (const int4*)idx;
    const float2* tbl  = (const float2*)tables;

    const int gw = blockIdx.x * 4 + wave;
    const int tile0 = gw * tiles_per_wave;

    int4 iv = idx4[(tile0 * 16 + m) * 4 + q];
    float2 g0 = tbl[(q * 4 + 0) * MTBL + iv.x];
    float2 g1 = tbl[(q * 4 + 1) * MTBL + iv.y];
    float2 g2 = tbl[(q * 4 + 2) * MTBL + iv.z];
    float2 g3 = tbl[(q * 4 + 3) * MTBL + iv.w];

    for (int it = 0; it < tiles_per_wave; ++it) {
        const int pbase = (tile0 + it) * 16;
        const bool more = (it + 1) < tiles_per_wave;

        short8 Bx;
        {
            unsigned int p0 = pack2bf(g0.x, g0.y);
            unsigned int p1 = pack2bf(g1.x, g1.y);
            unsigned int p2 = pack2bf(g2.x, g2.y);
            unsigned int p3 = pack2bf(g3.x, g3.y);
            Bx[0] = (short)(p0 & 0xFFFF); Bx[1] = (short)(p0 >> 16);
            Bx[2] = (short)(p1 & 0xFFFF); Bx[3] = (short)(p1 >> 16);
            Bx[4] = (short)(p2 & 0xFFFF); Bx[5] = (short)(p2 >> 16);
            Bx[6] = (short)(p3 & 0xFFFF); Bx[7] = (short)(p3 >> 16);
        }

        int4 ivn;
        if (more) ivn = idx4[((pbase + 16) + m) * 4 + q];

        floatx4 acc[4];
#pragma unroll
        for (int t = 0; t < 4; ++t)
            acc[t] = __builtin_amdgcn_mfma_f32_16x16x32_bf16(A1[t], Bx, C1[t], 0, 0, 0);

#pragma unroll
        for (int t = 0; t < 4; ++t) {
            uint2 pk;
            pk.x = pack2bf(fmaxf(acc[t][0], 0.f), fmaxf(acc[t][1], 0.f));
            pk.y = pack2bf(fmaxf(acc[t][2], 0.f), fmaxf(acc[t][3], 0.f));
            *(uint2*)(hrow + t * 16 + q * 4) = pk;
        }
        short8 Bh0 = *(const short8*)(hrow + q * 8);
        short8 Bh1 = *(const short8*)(hrow + 32 + q * 8);

#pragma unroll
        for (int t = 0; t < 4; ++t) {
            acc[t] = __builtin_amdgcn_mfma_f32_16x16x32_bf16(A2[t][0], Bh0, C2[t], 0, 0, 0);
            acc[t] = __builtin_amdgcn_mfma_f32_16x16x32_bf16(A2[t][1], Bh1, acc[t], 0, 0, 0);
        }

        if (more) {
            g0 = tbl[(q * 4 + 0) * MTBL + ivn.x];
            g1 = tbl[(q * 4 + 1) * MTBL + ivn.y];
            g2 = tbl[(q * 4 + 2) * MTBL + ivn.z];
            g3 = tbl[(q * 4 + 3) * MTBL + ivn.w];
        }

#pragma unroll
        for (int t = 0; t < 4; ++t) {
            uint2 pk;
            pk.x = pack2bf(fmaxf(acc[t][0], 0.f), fmaxf(acc[t][1], 0.f));
            pk.y = pack2bf(fmaxf(acc[t][2], 0.f), fmaxf(acc[t][3], 0.f));
            *(uint2*)(hrow + t * 16 + q * 4) = pk;
        }
        Bh0 = *(const short8*)(hrow + q * 8);
        Bh1 = *(const short8*)(hrow + 32 + q * 8);

#pragma unroll
        for (int t = 0; t < 4; ++t) {
            acc[t] = __builtin_amdgcn_mfma_f32_16x16x32_bf16(A3[t][0], Bh0, C3[t], 0, 0, 0);
            acc[t] = __builtin_amdgcn_mfma_f32_16x16x32_bf16(A3[t][1], Bh1, acc[t], 0, 0, 0);
        }

#pragma unroll
        for (int t = 0; t < 4; ++t) {
            uint2 pk;
            pk.x = pack2bf(fmaxf(acc[t][0], 0.f), fmaxf(acc[t][1], 0.f));
            pk.y = pack2bf(fmaxf(acc[t][2], 0.f), fmaxf(acc[t][3], 0.f));
            *(uint2*)(hrow + t * 16 + q * 4) = pk;
        }
        Bh0 = *(const short8*)(hrow + q * 8);
        Bh1 = *(const short8*)(hrow + 32 + q * 8);

        floatx4 o;
        o = __builtin_amdgcn_mfma_f32_16x16x32_bf16(A4[0], Bh0, C4, 0, 0, 0);
        o = __builtin_amdgcn_mfma_f32_16x16x32_bf16(A4[1], Bh1, o, 0, 0, 0);

        if (q == 0) {
            const int pn = pbase + m;
            out[pn * 3 + 0] = o[0];
            out[pn * 3 + 1] = o[1];
            out[pn * 3 + 2] = o[2];
        }
    }
}

extern "C" void kernel_launch(void* const* d_in, const int* in_sizes, int n_in,
                              void* d_out, int out_size, void* d_ws, size_t ws_size,
                              hipStream_t stream) {
    const int*   idx    = (const int*)d_in[0];
    const float* tables = (const float*)d_in[1];
    const float* W1 = (const float*)d_in[2];
    const float* b1 = (const float*)d_in[3];
    const float* W2 = (const float*)d_in[4];
    const float* b2 = (const float*)d_in[5];
    const float* W3 = (const float*)d_in[6];
    const float* b3 = (const float*)d_in[7];
    const float* W4 = (const float*)d_in[8];
    const float* b4 = (const float*)d_in[9];
    float* out = (float*)d_out;

    const int N = in_sizes[0] / 16;            // points (2,097,152)
    const int total_tiles = N / 16;

    const size_t idxT_bytes = (size_t)16 * N * 4;           // 128 MiB
    const size_t xU_bytes   = (size_t)16 * N * 4;           // 128 MiB
    const size_t tblC_bytes = (size_t)16 * MTBL * 4;        // 32 MiB
    const size_t need = idxT_bytes + xU_bytes + tblC_bytes;

    if (ws_size >= need) {
        int*          idxT = (int*)d_ws;
        unsigned int* xU   = (unsigned int*)((char*)d_ws + idxT_bytes);
        unsigned int* tblC = (unsigned int*)((char*)d_ws + idxT_bytes + xU_bytes);

        // P: fused transpose + compress
        const int tblocks = N / 1024;
        const int cblocks = (16 * MTBL) / 1024;
        ngp_prep<<<tblocks + cblocks, 256, 0, stream>>>(
            idx, idxT, (const floatx4*)tables, tblC, N);
        // B: two gather phases, one head per XCD each, 16 gathers in flight
        const int iters = (N >> 8) >> 12;   // points/block / 4096
        ngp_gather_ph<<<2048, 256, 0, stream>>>(idxT, tblC, xU, N, 0, iters);
        ngp_gather_ph<<<2048, 256, 0, stream>>>(idxT, tblC, xU, N, 1, iters);
        // C: MFMA MLP (lane-local transitions, 2-tile ILP, 24 KB LDS)
        const int blocks = 2048;
        const int tiles_per_wave = total_tiles / (blocks * 4);
        ngp_mlp<<<blocks, 256, 0, stream>>>(xU, W1, b1, W2, b2, W3, b3, W4, b4,
                                            out, N, tiles_per_wave);
    } else {
        const int blocks = 2048;
        const int tiles_per_wave = total_tiles / (blocks * 4);
        ngp_fused<<<blocks, 256, 0, stream>>>(idx, tables, W1, b1, W2, b2, W3, b3,
                                              W4, b4, out, tiles_per_wave);
    }
}

// Round 5
// 605.009 us; speedup vs baseline: 1.2559x; 1.1335x over previous
//
#include <hip/hip_runtime.h>
#include <hip/hip_bf16.h>

typedef __attribute__((ext_vector_type(8))) short short8;
typedef __attribute__((ext_vector_type(4))) float floatx4;
typedef __attribute__((ext_vector_type(4))) int int4v;
typedef __attribute__((ext_vector_type(4))) unsigned int uint4v;

#define MTBL 524288
#define HSTRIDE 72   // fallback kernel only

union U4S8 { uint4v u; short8 s; };

// fp32 -> bf16 round-to-nearest (weight preamble / prep kernels)
static __device__ __forceinline__ unsigned int pack2bf(float a, float b) {
    union { float f; unsigned int u; } x, y;
    x.f = a; y.f = b;
    unsigned int lo = (x.u + 0x8000u) >> 16;
    unsigned int hi = (y.u + 0x8000u) & 0xFFFF0000u;
    return lo | hi;
}
static __device__ __forceinline__ short bf1(float a) {
    union { float f; unsigned int u; } x;
    x.f = a;
    return (short)((x.u + 0x8000u) >> 16);
}

// relu + bf16-pack two acc registers into one MFMA B-fragment (8 bf16).
// __float22bfloat162_rn lowers to v_cvt_pk_bf16_f32 (1 instr / 2 values,
// RTNE) - replaces ~5 integer VALU ops per pair from the manual packing.
static __device__ __forceinline__ short8 relu_pack(floatx4 a, floatx4 b) {
    union { __hip_bfloat162 h2[4]; short8 s; } r;
    r.h2[0] = __float22bfloat162_rn(make_float2(fmaxf(a[0], 0.f), fmaxf(a[1], 0.f)));
    r.h2[1] = __float22bfloat162_rn(make_float2(fmaxf(a[2], 0.f), fmaxf(a[3], 0.f)));
    r.h2[2] = __float22bfloat162_rn(make_float2(fmaxf(b[0], 0.f), fmaxf(b[1], 0.f)));
    r.h2[3] = __float22bfloat162_rn(make_float2(fmaxf(b[2], 0.f), fmaxf(b[3], 0.f)));
    return r.s;
}

// one full MLP chain for a 16-point tile, lane-local transitions.
// Layout trick (R1): A-fragment t covers permuted output columns
//   c_t(p) = 32*(t>>1) + 4*(t&1) + 8*(p>>2) + (p&3)
// so lane (q,m) holds h[32*(t>>1)+4*(t&1)+8q+r] in acc[t][r] and the next
// layer's B-fragment is relu_pack of the SAME lane's accumulators.
static __device__ __forceinline__ floatx4 mlp_chain(
    uint4v cur,
    const short8 (&A1)[4], const short8 (&A2)[4][2], const short8 (&A3)[4][2],
    const short8 (&A4)[2],
    const floatx4 (&C1)[4], const floatx4 (&C2)[4], const floatx4 (&C3)[4],
    floatx4 C4)
{
    U4S8 bx; bx.u = cur;
    const short8 Bx = bx.s;

    floatx4 h[4];
#pragma unroll
    for (int t = 0; t < 4; ++t)
        h[t] = __builtin_amdgcn_mfma_f32_16x16x32_bf16(A1[t], Bx, C1[t], 0, 0, 0);
    short8 B0 = relu_pack(h[0], h[1]);
    short8 B1 = relu_pack(h[2], h[3]);

#pragma unroll
    for (int t = 0; t < 4; ++t) {
        h[t] = __builtin_amdgcn_mfma_f32_16x16x32_bf16(A2[t][0], B0, C2[t], 0, 0, 0);
        h[t] = __builtin_amdgcn_mfma_f32_16x16x32_bf16(A2[t][1], B1, h[t], 0, 0, 0);
    }
    B0 = relu_pack(h[0], h[1]);
    B1 = relu_pack(h[2], h[3]);

#pragma unroll
    for (int t = 0; t < 4; ++t) {
        h[t] = __builtin_amdgcn_mfma_f32_16x16x32_bf16(A3[t][0], B0, C3[t], 0, 0, 0);
        h[t] = __builtin_amdgcn_mfma_f32_16x16x32_bf16(A3[t][1], B1, h[t], 0, 0, 0);
    }
    B0 = relu_pack(h[0], h[1]);
    B1 = relu_pack(h[2], h[3]);

    floatx4 o;
    o = __builtin_amdgcn_mfma_f32_16x16x32_bf16(A4[0], B0, C4, 0, 0, 0);
    o = __builtin_amdgcn_mfma_f32_16x16x32_bf16(A4[1], B1, o, 0, 0, 0);
    return o;
}

// ---------------- Kernel P: fused prep ----------------
// blocks [0, N/1024):           transpose idx [N][16] -> idxT [16][N]
// blocks [N/1024, +16M/1024):   compress tables fp32 [16*M][2] -> packed bf16
__global__ __launch_bounds__(256) void ngp_prep(
    const int* __restrict__ idx, int* __restrict__ idxT,
    const floatx4* __restrict__ tab4, unsigned int* __restrict__ tblC, int N)
{
    const int tblocks = N >> 10;
    if ((int)blockIdx.x < tblocks) {
        const int t  = blockIdx.x * 256 + threadIdx.x;
        const int p0 = t * 4;
        const int4v* rows = (const int4v*)idx;
        int4v r[4][4];
#pragma unroll
        for (int p = 0; p < 4; ++p)
#pragma unroll
            for (int c = 0; c < 4; ++c)
                r[p][c] = __builtin_nontemporal_load(rows + (size_t)(p0 + p) * 4 + c);
#pragma unroll
        for (int c = 0; c < 4; ++c)
#pragma unroll
            for (int k = 0; k < 4; ++k) {
                const int h = c * 4 + k;
                int4v w;
                w[0] = r[0][c][k]; w[1] = r[1][c][k]; w[2] = r[2][c][k]; w[3] = r[3][c][k];
                __builtin_nontemporal_store(w, (int4v*)(idxT + (size_t)h * N + p0));
            }
    } else {
        const int t = (blockIdx.x - tblocks) * 256 + threadIdx.x;
        floatx4 a = __builtin_nontemporal_load(tab4 + (size_t)2 * t);
        floatx4 b = __builtin_nontemporal_load(tab4 + (size_t)2 * t + 1);
        uint4v w;
        w[0] = pack2bf(a[0], a[1]);
        w[1] = pack2bf(a[2], a[3]);
        w[2] = pack2bf(b[0], b[1]);
        w[3] = pack2bf(b[2], b[3]);
        __builtin_nontemporal_store(w, (uint4v*)(tblC + (size_t)4 * t));
    }
}

// ---------------- Kernel B: one-head-per-XCD gather phase ----------------
// head = (blk&7)*2 + phase; per-XCD live table slice = 2 MiB (bf16-packed)
// < 4 MiB L2 -> gathers are L2 hits.  8 points/thread/iter, 4 iterations,
// idx prefetched one iteration ahead (R0/R1-proven steady state; the R4
// 16-deep/2-iter variant regressed ~40 us/phase from prologue serialization).
__global__ __launch_bounds__(256) void ngp_gather_ph(
    const int* __restrict__ idxT, const unsigned int* __restrict__ tblC,
    unsigned int* __restrict__ xU, int N, int phase, int iters)
{
    const int h    = ((blockIdx.x & 7) << 1) | phase;
    const int slot = blockIdx.x >> 3;                 // 0..255
    const int* __restrict__ ih = idxT + (size_t)h * N;
    const unsigned int* __restrict__ th = tblC + (size_t)h * MTBL;
    unsigned int* __restrict__ xh = xU + (size_t)h * N;

    int p = slot * (N >> 8) + (threadIdx.x << 3);     // 8 points per thread per iter
    int4v iv0 = __builtin_nontemporal_load((const int4v*)(ih + p));
    int4v iv1 = __builtin_nontemporal_load((const int4v*)(ih + p + 4));
    for (int it = 0; it < iters; ++it) {
        int4v nv0 = iv0, nv1 = iv1;
        if (it + 1 < iters) {
            nv0 = __builtin_nontemporal_load((const int4v*)(ih + p + 2048));
            nv1 = __builtin_nontemporal_load((const int4v*)(ih + p + 2052));
        }
        uint4v w0, w1;
        w0[0] = th[iv0[0]]; w0[1] = th[iv0[1]]; w0[2] = th[iv0[2]]; w0[3] = th[iv0[3]];
        w1[0] = th[iv1[0]]; w1[1] = th[iv1[1]]; w1[2] = th[iv1[2]]; w1[3] = th[iv1[3]];
        __builtin_nontemporal_store(w0, (uint4v*)(xh + p));
        __builtin_nontemporal_store(w1, (uint4v*)(xh + p + 4));
        iv0 = nv0; iv1 = nv1;
        p += 2048;
    }
}

// ---------------- Kernel C: MFMA MLP on contiguous xU ----------------
// Lane-local layer transitions (no LDS in loop), 2 independent tiles per
// iteration (chain was latency-bound at MfmaUtil 12.6%), two-stage 24 KB
// weight staging for occupancy.
// launch_bounds (256,2): (256,4) forced VGPR=64 and spilled (R0 post-mortem).
__global__ __launch_bounds__(256, 2) void ngp_mlp(
    const unsigned int* __restrict__ xU,
    const float* __restrict__ W1, const float* __restrict__ b1,
    const float* __restrict__ W2, const float* __restrict__ b2,
    const float* __restrict__ W3, const float* __restrict__ b3,
    const float* __restrict__ W4, const float* __restrict__ b4,
    float* __restrict__ out, int N, int tiles_per_wave)
{
    __shared__ float sW[6144];   // 24 KB, reused across 2 staging stages

    const int tid  = threadIdx.x;
    const int wave = tid >> 6;
    const int lane = tid & 63;
    const int q = lane >> 4;
    const int m = lane & 15;

    int ct[4];
#pragma unroll
    for (int t = 0; t < 4; ++t)
        ct[t] = 32 * (t >> 1) + 4 * (t & 1) + 8 * (m >> 2) + (m & 3);

    short8 A1[4], A2[4][2], A3[4][2], A4[2];
    floatx4 C1[4], C2[4], C3[4], C4;

    // ---- stage A: W1 (2048) + W2 (4096) ----
    for (int i = tid; i < 2048; i += 256) sW[i] = W1[i];
    for (int i = tid; i < 4096; i += 256) sW[2048 + i] = W2[i];
    __syncthreads();
#pragma unroll
    for (int t = 0; t < 4; ++t) {
        short8 a;
#pragma unroll
        for (int j = 0; j < 8; ++j)
            a[j] = bf1(sW[(q * 8 + j) * 64 + ct[t]]);
        A1[t] = a;
    }
#pragma unroll
    for (int t = 0; t < 4; ++t)
#pragma unroll
        for (int c = 0; c < 2; ++c) {
            short8 a;
#pragma unroll
            for (int j = 0; j < 8; ++j)
                a[j] = bf1(sW[2048 + (c * 32 + q * 8 + j) * 64 + ct[t]]);
            A2[t][c] = a;
        }
    __syncthreads();

    // ---- stage B: W3 (4096) + W4 (192) + biases (195) ----
    for (int i = tid; i < 4096; i += 256) sW[i] = W3[i];
    if (tid < 192) sW[4096 + tid] = W4[tid];
    if (tid < 64)       sW[4288 + tid] = b1[tid];
    else if (tid < 128) sW[4288 + tid] = b2[tid - 64];
    else if (tid < 192) sW[4288 + tid] = b3[tid - 128];
    else if (tid < 195) sW[4288 + tid] = b4[tid - 192];
    __syncthreads();
#pragma unroll
    for (int t = 0; t < 4; ++t)
#pragma unroll
        for (int c = 0; c < 2; ++c) {
            short8 a;
#pragma unroll
            for (int j = 0; j < 8; ++j)
                a[j] = bf1(sW[(c * 32 + q * 8 + j) * 64 + ct[t]]);
            A3[t][c] = a;
        }
#pragma unroll
    for (int c = 0; c < 2; ++c) {
        short8 a;
#pragma unroll
        for (int j = 0; j < 8; ++j)
            a[j] = (m < 3) ? bf1(sW[4096 + (c * 32 + q * 8 + j) * 3 + m]) : (short)0;
        A4[c] = a;
    }
#pragma unroll
    for (int t = 0; t < 4; ++t) {
        const int bi = 32 * (t >> 1) + 4 * (t & 1) + 8 * q;   // permuted bias base
#pragma unroll
        for (int r = 0; r < 4; ++r) {
            C1[t][r] = sW[4288 + bi + r];
            C2[t][r] = sW[4288 + 64 + bi + r];
            C3[t][r] = sW[4288 + 128 + bi + r];
        }
    }
#pragma unroll
    for (int r = 0; r < 4; ++r)
        C4[r] = (q == 0 && r < 3) ? sW[4288 + 192 + r] : 0.0f;

    const int gw = blockIdx.x * 4 + wave;
    const int tile0 = gw * tiles_per_wave;
    const int iters = tiles_per_wave >> 1;    // 2 tiles per iteration

    const unsigned int* xr = xU + (size_t)(q * 4) * N + m;

    #define XLD(tile, c) __builtin_nontemporal_load(&xr[(size_t)(c) * N + (tile) * 16])

    uint4v curA, curB;
    {
        curA[0] = XLD(tile0, 0);     curA[1] = XLD(tile0, 1);
        curA[2] = XLD(tile0, 2);     curA[3] = XLD(tile0, 3);
        curB[0] = XLD(tile0 + 1, 0); curB[1] = XLD(tile0 + 1, 1);
        curB[2] = XLD(tile0 + 1, 2); curB[3] = XLD(tile0 + 1, 3);
    }

    for (int k = 0; k < iters; ++k) {
        const int pbaseA = (tile0 + 2 * k) * 16;
        const bool more = (k + 1) < iters;

        uint4v nxtA = curA, nxtB = curB;
        if (more) {
            const int tn = tile0 + 2 * k + 2;
            nxtA[0] = XLD(tn, 0);     nxtA[1] = XLD(tn, 1);
            nxtA[2] = XLD(tn, 2);     nxtA[3] = XLD(tn, 3);
            nxtB[0] = XLD(tn + 1, 0); nxtB[1] = XLD(tn + 1, 1);
            nxtB[2] = XLD(tn + 1, 2); nxtB[3] = XLD(tn + 1, 3);
        }

        floatx4 oA = mlp_chain(curA, A1, A2, A3, A4, C1, C2, C3, C4);
        floatx4 oB = mlp_chain(curB, A1, A2, A3, A4, C1, C2, C3, C4);

        if (q == 0) {
            const int pA = pbaseA + m;
            __builtin_nontemporal_store(oA[0], out + pA * 3 + 0);
            __builtin_nontemporal_store(oA[1], out + pA * 3 + 1);
            __builtin_nontemporal_store(oA[2], out + pA * 3 + 2);
            const int pB = pA + 16;
            __builtin_nontemporal_store(oB[0], out + pB * 3 + 0);
            __builtin_nontemporal_store(oB[1], out + pB * 3 + 1);
            __builtin_nontemporal_store(oB[2], out + pB * 3 + 2);
        }

        curA = nxtA;
        curB = nxtB;
    }
    #undef XLD
}

// ---------------- Fallback: fused kernel without workspace ----------------
__global__ __launch_bounds__(256, 2) void ngp_fused(
    const int* __restrict__ idx,
    const float* __restrict__ tables,
    const float* __restrict__ W1, const float* __restrict__ b1,
    const float* __restrict__ W2, const float* __restrict__ b2,
    const float* __restrict__ W3, const float* __restrict__ b3,
    const float* __restrict__ W4, const float* __restrict__ b4,
    float* __restrict__ out, int tiles_per_wave)
{
    __shared__ float sW1[2048];
    __shared__ float sW2[4096];
    __shared__ float sW3[4096];
    __shared__ float sW4[192];
    __shared__ float sB[200];
    __shared__ __hip_bfloat16 sH[4][16 * HSTRIDE];

    const int tid = threadIdx.x;
    for (int i = tid; i < 2048; i += 256) sW1[i] = W1[i];
    for (int i = tid; i < 4096; i += 256) sW2[i] = W2[i];
    for (int i = tid; i < 4096; i += 256) sW3[i] = W3[i];
    if (tid < 192) sW4[tid] = W4[tid];
    if (tid < 64)       sB[tid] = b1[tid];
    else if (tid < 128) sB[tid] = b2[tid - 64];
    else if (tid < 192) sB[tid] = b3[tid - 128];
    else if (tid < 195) sB[tid] = b4[tid - 192];
    __syncthreads();

    const int wave = tid >> 6;
    const int lane = tid & 63;
    const int q = lane >> 4;
    const int m = lane & 15;

    short8 A1[4], A2[4][2], A3[4][2], A4[2];
#pragma unroll
    for (int t = 0; t < 4; ++t) {
        short8 a;
#pragma unroll
        for (int j = 0; j < 8; ++j)
            a[j] = bf1(sW1[(q * 8 + j) * 64 + t * 16 + m]);
        A1[t] = a;
    }
#pragma unroll
    for (int t = 0; t < 4; ++t)
#pragma unroll
        for (int c = 0; c < 2; ++c) {
            short8 a, a3;
#pragma unroll
            for (int j = 0; j < 8; ++j) {
                a[j]  = bf1(sW2[(c * 32 + q * 8 + j) * 64 + t * 16 + m]);
                a3[j] = bf1(sW3[(c * 32 + q * 8 + j) * 64 + t * 16 + m]);
            }
            A2[t][c] = a;
            A3[t][c] = a3;
        }
#pragma unroll
    for (int c = 0; c < 2; ++c) {
        short8 a;
#pragma unroll
        for (int j = 0; j < 8; ++j)
            a[j] = (m < 3) ? bf1(sW4[(c * 32 + q * 8 + j) * 3 + m]) : (short)0;
        A4[c] = a;
    }

    floatx4 C1[4], C2[4], C3[4], C4;
#pragma unroll
    for (int t = 0; t < 4; ++t)
#pragma unroll
        for (int r = 0; r < 4; ++r) {
            C1[t][r] = sB[t * 16 + q * 4 + r];
            C2[t][r] = sB[64 + t * 16 + q * 4 + r];
            C3[t][r] = sB[128 + t * 16 + q * 4 + r];
        }
#pragma unroll
    for (int r = 0; r < 4; ++r)
        C4[r] = (q == 0 && r < 3) ? sB[192 + r] : 0.0f;

    __hip_bfloat16* hrow = &sH[wave][m * HSTRIDE];
    const int4*   idx4 = (const int4*)idx;
    const float2* tbl  = (const float2*)tables;

    const int gw = blockIdx.x * 4 + wave;
    const int tile0 = gw * tiles_per_wave;

    int4 iv = idx4[(tile0 * 16 + m) * 4 + q];
    float2 g0 = tbl[(q * 4 + 0) * MTBL + iv.x];
    float2 g1 = tbl[(q * 4 + 1) * MTBL + iv.y];
    float2 g2 = tbl[(q * 4 + 2) * MTBL + iv.z];
    float2 g3 = tbl[(q * 4 + 3) * MTBL + iv.w];

    for (int it = 0; it < tiles_per_wave; ++it) {
        const int pbase = (tile0 + it) * 16;
        const bool more = (it + 1) < tiles_per_wave;

        short8 Bx;
        {
            unsigned int p0 = pack2bf(g0.x, g0.y);
            unsigned int p1 = pack2bf(g1.x, g1.y);
            unsigned int p2 = pack2bf(g2.x, g2.y);
            unsigned int p3 = pack2bf(g3.x, g3.y);
            Bx[0] = (short)(p0 & 0xFFFF); Bx[1] = (short)(p0 >> 16);
            Bx[2] = (short)(p1 & 0xFFFF); Bx[3] = (short)(p1 >> 16);
            Bx[4] = (short)(p2 & 0xFFFF); Bx[5] = (short)(p2 >> 16);
            Bx[6] = (short)(p3 & 0xFFFF); Bx[7] = (short)(p3 >> 16);
        }

        int4 ivn;
        if (more) ivn = idx4[((pbase + 16) + m) * 4 + q];

        floatx4 acc[4];
#pragma unroll
        for (int t = 0; t < 4; ++t)
            acc[t] = __builtin_amdgcn_mfma_f32_16x16x32_bf16(A1[t], Bx, C1[t], 0, 0, 0);

#pragma unroll
        for (int t = 0; t < 4; ++t) {
            uint2 pk;
            pk.x = pack2bf(fmaxf(acc[t][0], 0.f), fmaxf(acc[t][1], 0.f));
            pk.y = pack2bf(fmaxf(acc[t][2], 0.f), fmaxf(acc[t][3], 0.f));
            *(uint2*)(hrow + t * 16 + q * 4) = pk;
        }
        short8 Bh0 = *(const short8*)(hrow + q * 8);
        short8 Bh1 = *(const short8*)(hrow + 32 + q * 8);

#pragma unroll
        for (int t = 0; t < 4; ++t) {
            acc[t] = __builtin_amdgcn_mfma_f32_16x16x32_bf16(A2[t][0], Bh0, C2[t], 0, 0, 0);
            acc[t] = __builtin_amdgcn_mfma_f32_16x16x32_bf16(A2[t][1], Bh1, acc[t], 0, 0, 0);
        }

        if (more) {
            g0 = tbl[(q * 4 + 0) * MTBL + ivn.x];
            g1 = tbl[(q * 4 + 1) * MTBL + ivn.y];
            g2 = tbl[(q * 4 + 2) * MTBL + ivn.z];
            g3 = tbl[(q * 4 + 3) * MTBL + ivn.w];
        }

#pragma unroll
        for (int t = 0; t < 4; ++t) {
            uint2 pk;
            pk.x = pack2bf(fmaxf(acc[t][0], 0.f), fmaxf(acc[t][1], 0.f));
            pk.y = pack2bf(fmaxf(acc[t][2], 0.f), fmaxf(acc[t][3], 0.f));
            *(uint2*)(hrow + t * 16 + q * 4) = pk;
        }
        Bh0 = *(const short8*)(hrow + q * 8);
        Bh1 = *(const short8*)(hrow + 32 + q * 8);

#pragma unroll
        for (int t = 0; t < 4; ++t) {
            acc[t] = __builtin_amdgcn_mfma_f32_16x16x32_bf16(A3[t][0], Bh0, C3[t], 0, 0, 0);
            acc[t] = __builtin_amdgcn_mfma_f32_16x16x32_bf16(A3[t][1], Bh1, acc[t], 0, 0, 0);
        }

#pragma unroll
        for (int t = 0; t < 4; ++t) {
            uint2 pk;
            pk.x = pack2bf(fmaxf(acc[t][0], 0.f), fmaxf(acc[t][1], 0.f));
            pk.y = pack2bf(fmaxf(acc[t][2], 0.f), fmaxf(acc[t][3], 0.f));
            *(uint2*)(hrow + t * 16 + q * 4) = pk;
        }
        Bh0 = *(const short8*)(hrow + q * 8);
        Bh1 = *(const short8*)(hrow + 32 + q * 8);

        floatx4 o;
        o = __builtin_amdgcn_mfma_f32_16x16x32_bf16(A4[0], Bh0, C4, 0, 0, 0);
        o = __builtin_amdgcn_mfma_f32_16x16x32_bf16(A4[1], Bh1, o, 0, 0, 0);

        if (q == 0) {
            const int pn = pbase + m;
            out[pn * 3 + 0] = o[0];
            out[pn * 3 + 1] = o[1];
            out[pn * 3 + 2] = o[2];
        }
    }
}

extern "C" void kernel_launch(void* const* d_in, const int* in_sizes, int n_in,
                              void* d_out, int out_size, void* d_ws, size_t ws_size,
                              hipStream_t stream) {
    const int*   idx    = (const int*)d_in[0];
    const float* tables = (const float*)d_in[1];
    const float* W1 = (const float*)d_in[2];
    const float* b1 = (const float*)d_in[3];
    const float* W2 = (const float*)d_in[4];
    const float* b2 = (const float*)d_in[5];
    const float* W3 = (const float*)d_in[6];
    const float* b3 = (const float*)d_in[7];
    const float* W4 = (const float*)d_in[8];
    const float* b4 = (const float*)d_in[9];
    float* out = (float*)d_out;

    const int N = in_sizes[0] / 16;            // points (2,097,152)
    const int total_tiles = N / 16;

    const size_t idxT_bytes = (size_t)16 * N * 4;           // 128 MiB
    const size_t xU_bytes   = (size_t)16 * N * 4;           // 128 MiB
    const size_t tblC_bytes = (size_t)16 * MTBL * 4;        // 32 MiB
    const size_t need = idxT_bytes + xU_bytes + tblC_bytes;

    if (ws_size >= need) {
        int*          idxT = (int*)d_ws;
        unsigned int* xU   = (unsigned int*)((char*)d_ws + idxT_bytes);
        unsigned int* tblC = (unsigned int*)((char*)d_ws + idxT_bytes + xU_bytes);

        // P: fused transpose + compress
        const int tblocks = N / 1024;
        const int cblocks = (16 * MTBL) / 1024;
        ngp_prep<<<tblocks + cblocks, 256, 0, stream>>>(
            idx, idxT, (const floatx4*)tables, tblC, N);
        // B: two gather phases, one head per XCD each (R1-proven 8/iter form)
        const int iters = (N >> 8) >> 11;   // points/block / 2048 = 4
        ngp_gather_ph<<<2048, 256, 0, stream>>>(idxT, tblC, xU, N, 0, iters);
        ngp_gather_ph<<<2048, 256, 0, stream>>>(idxT, tblC, xU, N, 1, iters);
        // C: MFMA MLP (lane-local transitions, 2-tile ILP, 24 KB LDS)
        const int blocks = 2048;
        const int tiles_per_wave = total_tiles / (blocks * 4);
        ngp_mlp<<<blocks, 256, 0, stream>>>(xU, W1, b1, W2, b2, W3, b3, W4, b4,
                                            out, N, tiles_per_wave);
    } else {
        const int blocks = 2048;
        const int tiles_per_wave = total_tiles / (blocks * 4);
        ngp_fused<<<blocks, 256, 0, stream>>>(idx, tables, W1, b1, W2, b2, W3, b3,
                                              W4, b4, out, tiles_per_wave);
    }
}

// Round 6
// 589.174 us; speedup vs baseline: 1.2897x; 1.0269x over previous
//
#include <hip/hip_runtime.h>
#include <hip/hip_bf16.h>

typedef __attribute__((ext_vector_type(8))) short short8;
typedef __attribute__((ext_vector_type(4))) float floatx4;
typedef __attribute__((ext_vector_type(4))) int int4v;
typedef __attribute__((ext_vector_type(4))) unsigned int uint4v;

#define MTBL 524288
#define HSTRIDE 72   // fallback kernel only

union U4S8 { uint4v u; short8 s; };

// fp32 -> bf16 round-to-nearest (weight preamble / prep kernels)
static __device__ __forceinline__ unsigned int pack2bf(float a, float b) {
    union { float f; unsigned int u; } x, y;
    x.f = a; y.f = b;
    unsigned int lo = (x.u + 0x8000u) >> 16;
    unsigned int hi = (y.u + 0x8000u) & 0xFFFF0000u;
    return lo | hi;
}
static __device__ __forceinline__ short bf1(float a) {
    union { float f; unsigned int u; } x;
    x.f = a;
    return (short)((x.u + 0x8000u) >> 16);
}

// relu + bf16-pack two acc registers into one MFMA B-fragment (8 bf16).
// __float22bfloat162_rn lowers to v_cvt_pk_bf16_f32 (1 instr / 2 values).
static __device__ __forceinline__ short8 relu_pack(floatx4 a, floatx4 b) {
    union { __hip_bfloat162 h2[4]; short8 s; } r;
    r.h2[0] = __float22bfloat162_rn(make_float2(fmaxf(a[0], 0.f), fmaxf(a[1], 0.f)));
    r.h2[1] = __float22bfloat162_rn(make_float2(fmaxf(a[2], 0.f), fmaxf(a[3], 0.f)));
    r.h2[2] = __float22bfloat162_rn(make_float2(fmaxf(b[0], 0.f), fmaxf(b[1], 0.f)));
    r.h2[3] = __float22bfloat162_rn(make_float2(fmaxf(b[2], 0.f), fmaxf(b[3], 0.f)));
    return r.s;
}

// one full MLP chain for a 16-point tile, lane-local transitions.
// Layout trick (R1): A-fragment t covers permuted output columns
//   c_t(p) = 32*(t>>1) + 4*(t&1) + 8*(p>>2) + (p&3)
// so lane (q,m) holds h[32*(t>>1)+4*(t&1)+8q+r] in acc[t][r] and the next
// layer's B-fragment is relu_pack of the SAME lane's accumulators.
static __device__ __forceinline__ floatx4 mlp_chain(
    uint4v cur,
    const short8 (&A1)[4], const short8 (&A2)[4][2], const short8 (&A3)[4][2],
    const short8 (&A4)[2],
    const floatx4 (&C1)[4], const floatx4 (&C2)[4], const floatx4 (&C3)[4],
    floatx4 C4)
{
    U4S8 bx; bx.u = cur;
    const short8 Bx = bx.s;

    floatx4 h[4];
#pragma unroll
    for (int t = 0; t < 4; ++t)
        h[t] = __builtin_amdgcn_mfma_f32_16x16x32_bf16(A1[t], Bx, C1[t], 0, 0, 0);
    short8 B0 = relu_pack(h[0], h[1]);
    short8 B1 = relu_pack(h[2], h[3]);

#pragma unroll
    for (int t = 0; t < 4; ++t) {
        h[t] = __builtin_amdgcn_mfma_f32_16x16x32_bf16(A2[t][0], B0, C2[t], 0, 0, 0);
        h[t] = __builtin_amdgcn_mfma_f32_16x16x32_bf16(A2[t][1], B1, h[t], 0, 0, 0);
    }
    B0 = relu_pack(h[0], h[1]);
    B1 = relu_pack(h[2], h[3]);

#pragma unroll
    for (int t = 0; t < 4; ++t) {
        h[t] = __builtin_amdgcn_mfma_f32_16x16x32_bf16(A3[t][0], B0, C3[t], 0, 0, 0);
        h[t] = __builtin_amdgcn_mfma_f32_16x16x32_bf16(A3[t][1], B1, h[t], 0, 0, 0);
    }
    B0 = relu_pack(h[0], h[1]);
    B1 = relu_pack(h[2], h[3]);

    floatx4 o;
    o = __builtin_amdgcn_mfma_f32_16x16x32_bf16(A4[0], B0, C4, 0, 0, 0);
    o = __builtin_amdgcn_mfma_f32_16x16x32_bf16(A4[1], B1, o, 0, 0, 0);
    return o;
}

// ---------------- Kernel P: fused prep ----------------
// blocks [0, N/1024):           transpose idx [N][16] -> idxT [16][N]
// blocks [N/1024, +16M/1024):   compress tables fp32 [16*M][2] -> packed bf16
// Loads are PLAIN (cached): the transpose's four 16-B reads per row share one
// 64-B line (4x same-line reuse), and the 6.3 TB/s copy ceiling was measured
// with cached loads.  NT only on the write-once stores.
__global__ __launch_bounds__(256) void ngp_prep(
    const int* __restrict__ idx, int* __restrict__ idxT,
    const floatx4* __restrict__ tab4, unsigned int* __restrict__ tblC, int N)
{
    const int tblocks = N >> 10;
    if ((int)blockIdx.x < tblocks) {
        const int t  = blockIdx.x * 256 + threadIdx.x;
        const int p0 = t * 4;
        const int4v* rows = (const int4v*)idx;
        int4v r[4][4];
#pragma unroll
        for (int p = 0; p < 4; ++p)
#pragma unroll
            for (int c = 0; c < 4; ++c)
                r[p][c] = rows[(size_t)(p0 + p) * 4 + c];
#pragma unroll
        for (int c = 0; c < 4; ++c)
#pragma unroll
            for (int k = 0; k < 4; ++k) {
                const int h = c * 4 + k;
                int4v w;
                w[0] = r[0][c][k]; w[1] = r[1][c][k]; w[2] = r[2][c][k]; w[3] = r[3][c][k];
                __builtin_nontemporal_store(w, (int4v*)(idxT + (size_t)h * N + p0));
            }
    } else {
        const int t = (blockIdx.x - tblocks) * 256 + threadIdx.x;
        floatx4 a = tab4[(size_t)2 * t];
        floatx4 b = tab4[(size_t)2 * t + 1];
        uint4v w;
        w[0] = pack2bf(a[0], a[1]);
        w[1] = pack2bf(a[2], a[3]);
        w[2] = pack2bf(b[0], b[1]);
        w[3] = pack2bf(b[2], b[3]);
        __builtin_nontemporal_store(w, (uint4v*)(tblC + (size_t)4 * t));
    }
}

// ---------------- Kernel B: one-head-per-XCD gather, both phases ----------------
// 4096 blocks: phase = bit 11 of blockIdx (blocks 0..2047 -> even heads,
// 2048..4095 -> odd heads); XCD = blockIdx & 7 (round-robin).  Per-XCD live
// table slice 2 MiB (both-phase co-residency worst case 4 MiB = L2).  idxT
// reads are NT (no-allocate) so the table keeps L2.  8 points/thread/iter,
// idx prefetched one iteration ahead (R5-verified steady state).
__global__ __launch_bounds__(256) void ngp_gather(
    const int* __restrict__ idxT, const unsigned int* __restrict__ tblC,
    unsigned int* __restrict__ xU, int N, int iters)
{
    const int phase = (blockIdx.x >> 11) & 1;
    const int blk   = blockIdx.x & 2047;
    const int h     = ((blk & 7) << 1) | phase;
    const int slot  = blk >> 3;                       // 0..255
    const int* __restrict__ ih = idxT + (size_t)h * N;
    const unsigned int* __restrict__ th = tblC + (size_t)h * MTBL;
    unsigned int* __restrict__ xh = xU + (size_t)h * N;

    int p = slot * (N >> 8) + (threadIdx.x << 3);     // 8 points per thread per iter
    int4v iv0 = __builtin_nontemporal_load((const int4v*)(ih + p));
    int4v iv1 = __builtin_nontemporal_load((const int4v*)(ih + p + 4));
    for (int it = 0; it < iters; ++it) {
        int4v nv0 = iv0, nv1 = iv1;
        if (it + 1 < iters) {
            nv0 = __builtin_nontemporal_load((const int4v*)(ih + p + 2048));
            nv1 = __builtin_nontemporal_load((const int4v*)(ih + p + 2052));
        }
        uint4v w0, w1;
        w0[0] = th[iv0[0]]; w0[1] = th[iv0[1]]; w0[2] = th[iv0[2]]; w0[3] = th[iv0[3]];
        w1[0] = th[iv1[0]]; w1[1] = th[iv1[1]]; w1[2] = th[iv1[2]]; w1[3] = th[iv1[3]];
        __builtin_nontemporal_store(w0, (uint4v*)(xh + p));
        __builtin_nontemporal_store(w1, (uint4v*)(xh + p + 4));
        iv0 = nv0; iv1 = nv1;
        p += 2048;
    }
}

// ---------------- Kernel C: MFMA MLP on contiguous xU ----------------
// Lane-local layer transitions (no LDS in loop), 2 independent tiles per
// iteration, two-stage 24 KB weight staging.  4096 blocks (tiles_per_wave=8):
// shorter tail + more resident blocks for the latency-bound chain.
// launch_bounds (256,2): (256,4) forced VGPR=64 and spilled (R0 post-mortem).
__global__ __launch_bounds__(256, 2) void ngp_mlp(
    const unsigned int* __restrict__ xU,
    const float* __restrict__ W1, const float* __restrict__ b1,
    const float* __restrict__ W2, const float* __restrict__ b2,
    const float* __restrict__ W3, const float* __restrict__ b3,
    const float* __restrict__ W4, const float* __restrict__ b4,
    float* __restrict__ out, int N, int tiles_per_wave)
{
    __shared__ float sW[6144];   // 24 KB, reused across 2 staging stages

    const int tid  = threadIdx.x;
    const int wave = tid >> 6;
    const int lane = tid & 63;
    const int q = lane >> 4;
    const int m = lane & 15;

    int ct[4];
#pragma unroll
    for (int t = 0; t < 4; ++t)
        ct[t] = 32 * (t >> 1) + 4 * (t & 1) + 8 * (m >> 2) + (m & 3);

    short8 A1[4], A2[4][2], A3[4][2], A4[2];
    floatx4 C1[4], C2[4], C3[4], C4;

    // ---- stage A: W1 (2048) + W2 (4096) ----
    for (int i = tid; i < 2048; i += 256) sW[i] = W1[i];
    for (int i = tid; i < 4096; i += 256) sW[2048 + i] = W2[i];
    __syncthreads();
#pragma unroll
    for (int t = 0; t < 4; ++t) {
        short8 a;
#pragma unroll
        for (int j = 0; j < 8; ++j)
            a[j] = bf1(sW[(q * 8 + j) * 64 + ct[t]]);
        A1[t] = a;
    }
#pragma unroll
    for (int t = 0; t < 4; ++t)
#pragma unroll
        for (int c = 0; c < 2; ++c) {
            short8 a;
#pragma unroll
            for (int j = 0; j < 8; ++j)
                a[j] = bf1(sW[2048 + (c * 32 + q * 8 + j) * 64 + ct[t]]);
            A2[t][c] = a;
        }
    __syncthreads();

    // ---- stage B: W3 (4096) + W4 (192) + biases (195) ----
    for (int i = tid; i < 4096; i += 256) sW[i] = W3[i];
    if (tid < 192) sW[4096 + tid] = W4[tid];
    if (tid < 64)       sW[4288 + tid] = b1[tid];
    else if (tid < 128) sW[4288 + tid] = b2[tid - 64];
    else if (tid < 192) sW[4288 + tid] = b3[tid - 128];
    else if (tid < 195) sW[4288 + tid] = b4[tid - 192];
    __syncthreads();
#pragma unroll
    for (int t = 0; t < 4; ++t)
#pragma unroll
        for (int c = 0; c < 2; ++c) {
            short8 a;
#pragma unroll
            for (int j = 0; j < 8; ++j)
                a[j] = bf1(sW[(c * 32 + q * 8 + j) * 64 + ct[t]]);
            A3[t][c] = a;
        }
#pragma unroll
    for (int c = 0; c < 2; ++c) {
        short8 a;
#pragma unroll
        for (int j = 0; j < 8; ++j)
            a[j] = (m < 3) ? bf1(sW[4096 + (c * 32 + q * 8 + j) * 3 + m]) : (short)0;
        A4[c] = a;
    }
#pragma unroll
    for (int t = 0; t < 4; ++t) {
        const int bi = 32 * (t >> 1) + 4 * (t & 1) + 8 * q;   // permuted bias base
#pragma unroll
        for (int r = 0; r < 4; ++r) {
            C1[t][r] = sW[4288 + bi + r];
            C2[t][r] = sW[4288 + 64 + bi + r];
            C3[t][r] = sW[4288 + 128 + bi + r];
        }
    }
#pragma unroll
    for (int r = 0; r < 4; ++r)
        C4[r] = (q == 0 && r < 3) ? sW[4288 + 192 + r] : 0.0f;

    const int gw = blockIdx.x * 4 + wave;
    const int tile0 = gw * tiles_per_wave;
    const int iters = tiles_per_wave >> 1;    // 2 tiles per iteration

    const unsigned int* xr = xU + (size_t)(q * 4) * N + m;

    #define XLD(tile, c) __builtin_nontemporal_load(&xr[(size_t)(c) * N + (tile) * 16])

    uint4v curA, curB;
    {
        curA[0] = XLD(tile0, 0);     curA[1] = XLD(tile0, 1);
        curA[2] = XLD(tile0, 2);     curA[3] = XLD(tile0, 3);
        curB[0] = XLD(tile0 + 1, 0); curB[1] = XLD(tile0 + 1, 1);
        curB[2] = XLD(tile0 + 1, 2); curB[3] = XLD(tile0 + 1, 3);
    }

    for (int k = 0; k < iters; ++k) {
        const int pbaseA = (tile0 + 2 * k) * 16;
        const bool more = (k + 1) < iters;

        uint4v nxtA = curA, nxtB = curB;
        if (more) {
            const int tn = tile0 + 2 * k + 2;
            nxtA[0] = XLD(tn, 0);     nxtA[1] = XLD(tn, 1);
            nxtA[2] = XLD(tn, 2);     nxtA[3] = XLD(tn, 3);
            nxtB[0] = XLD(tn + 1, 0); nxtB[1] = XLD(tn + 1, 1);
            nxtB[2] = XLD(tn + 1, 2); nxtB[3] = XLD(tn + 1, 3);
        }

        floatx4 oA = mlp_chain(curA, A1, A2, A3, A4, C1, C2, C3, C4);
        floatx4 oB = mlp_chain(curB, A1, A2, A3, A4, C1, C2, C3, C4);

        if (q == 0) {
            const int pA = pbaseA + m;
            __builtin_nontemporal_store(oA[0], out + pA * 3 + 0);
            __builtin_nontemporal_store(oA[1], out + pA * 3 + 1);
            __builtin_nontemporal_store(oA[2], out + pA * 3 + 2);
            const int pB = pA + 16;
            __builtin_nontemporal_store(oB[0], out + pB * 3 + 0);
            __builtin_nontemporal_store(oB[1], out + pB * 3 + 1);
            __builtin_nontemporal_store(oB[2], out + pB * 3 + 2);
        }

        curA = nxtA;
        curB = nxtB;
    }
    #undef XLD
}

// ---------------- Fallback: fused kernel without workspace ----------------
__global__ __launch_bounds__(256, 2) void ngp_fused(
    const int* __restrict__ idx,
    const float* __restrict__ tables,
    const float* __restrict__ W1, const float* __restrict__ b1,
    const float* __restrict__ W2, const float* __restrict__ b2,
    const float* __restrict__ W3, const float* __restrict__ b3,
    const float* __restrict__ W4, const float* __restrict__ b4,
    float* __restrict__ out, int tiles_per_wave)
{
    __shared__ float sW1[2048];
    __shared__ float sW2[4096];
    __shared__ float sW3[4096];
    __shared__ float sW4[192];
    __shared__ float sB[200];
    __shared__ __hip_bfloat16 sH[4][16 * HSTRIDE];

    const int tid = threadIdx.x;
    for (int i = tid; i < 2048; i += 256) sW1[i] = W1[i];
    for (int i = tid; i < 4096; i += 256) sW2[i] = W2[i];
    for (int i = tid; i < 4096; i += 256) sW3[i] = W3[i];
    if (tid < 192) sW4[tid] = W4[tid];
    if (tid < 64)       sB[tid] = b1[tid];
    else if (tid < 128) sB[tid] = b2[tid - 64];
    else if (tid < 192) sB[tid] = b3[tid - 128];
    else if (tid < 195) sB[tid] = b4[tid - 192];
    __syncthreads();

    const int wave = tid >> 6;
    const int lane = tid & 63;
    const int q = lane >> 4;
    const int m = lane & 15;

    short8 A1[4], A2[4][2], A3[4][2], A4[2];
#pragma unroll
    for (int t = 0; t < 4; ++t) {
        short8 a;
#pragma unroll
        for (int j = 0; j < 8; ++j)
            a[j] = bf1(sW1[(q * 8 + j) * 64 + t * 16 + m]);
        A1[t] = a;
    }
#pragma unroll
    for (int t = 0; t < 4; ++t)
#pragma unroll
        for (int c = 0; c < 2; ++c) {
            short8 a, a3;
#pragma unroll
            for (int j = 0; j < 8; ++j) {
                a[j]  = bf1(sW2[(c * 32 + q * 8 + j) * 64 + t * 16 + m]);
                a3[j] = bf1(sW3[(c * 32 + q * 8 + j) * 64 + t * 16 + m]);
            }
            A2[t][c] = a;
            A3[t][c] = a3;
        }
#pragma unroll
    for (int c = 0; c < 2; ++c) {
        short8 a;
#pragma unroll
        for (int j = 0; j < 8; ++j)
            a[j] = (m < 3) ? bf1(sW4[(c * 32 + q * 8 + j) * 3 + m]) : (short)0;
        A4[c] = a;
    }

    floatx4 C1[4], C2[4], C3[4], C4;
#pragma unroll
    for (int t = 0; t < 4; ++t)
#pragma unroll
        for (int r = 0; r < 4; ++r) {
            C1[t][r] = sB[t * 16 + q * 4 + r];
            C2[t][r] = sB[64 + t * 16 + q * 4 + r];
            C3[t][r] = sB[128 + t * 16 + q * 4 + r];
        }
#pragma unroll
    for (int r = 0; r < 4; ++r)
        C4[r] = (q == 0 && r < 3) ? sB[192 + r] : 0.0f;

    __hip_bfloat16* hrow = &sH[wave][m * HSTRIDE];
    const int4*   idx4 = (const int4*)idx;
    const float2* tbl  = (const float2*)tables;

    const int gw = blockIdx.x * 4 + wave;
    const int tile0 = gw * tiles_per_wave;

    int4 iv = idx4[(tile0 * 16 + m) * 4 + q];
    float2 g0 = tbl[(q * 4 + 0) * MTBL + iv.x];
    float2 g1 = tbl[(q * 4 + 1) * MTBL + iv.y];
    float2 g2 = tbl[(q * 4 + 2) * MTBL + iv.z];
    float2 g3 = tbl[(q * 4 + 3) * MTBL + iv.w];

    for (int it = 0; it < tiles_per_wave; ++it) {
        const int pbase = (tile0 + it) * 16;
        const bool more = (it + 1) < tiles_per_wave;

        short8 Bx;
        {
            unsigned int p0 = pack2bf(g0.x, g0.y);
            unsigned int p1 = pack2bf(g1.x, g1.y);
            unsigned int p2 = pack2bf(g2.x, g2.y);
            unsigned int p3 = pack2bf(g3.x, g3.y);
            Bx[0] = (short)(p0 & 0xFFFF); Bx[1] = (short)(p0 >> 16);
            Bx[2] = (short)(p1 & 0xFFFF); Bx[3] = (short)(p1 >> 16);
            Bx[4] = (short)(p2 & 0xFFFF); Bx[5] = (short)(p2 >> 16);
            Bx[6] = (short)(p3 & 0xFFFF); Bx[7] = (short)(p3 >> 16);
        }

        int4 ivn;
        if (more) ivn = idx4[((pbase + 16) + m) * 4 + q];

        floatx4 acc[4];
#pragma unroll
        for (int t = 0; t < 4; ++t)
            acc[t] = __builtin_amdgcn_mfma_f32_16x16x32_bf16(A1[t], Bx, C1[t], 0, 0, 0);

#pragma unroll
        for (int t = 0; t < 4; ++t) {
            uint2 pk;
            pk.x = pack2bf(fmaxf(acc[t][0], 0.f), fmaxf(acc[t][1], 0.f));
            pk.y = pack2bf(fmaxf(acc[t][2], 0.f), fmaxf(acc[t][3], 0.f));
            *(uint2*)(hrow + t * 16 + q * 4) = pk;
        }
        short8 Bh0 = *(const short8*)(hrow + q * 8);
        short8 Bh1 = *(const short8*)(hrow + 32 + q * 8);

#pragma unroll
        for (int t = 0; t < 4; ++t) {
            acc[t] = __builtin_amdgcn_mfma_f32_16x16x32_bf16(A2[t][0], Bh0, C2[t], 0, 0, 0);
            acc[t] = __builtin_amdgcn_mfma_f32_16x16x32_bf16(A2[t][1], Bh1, acc[t], 0, 0, 0);
        }

        if (more) {
            g0 = tbl[(q * 4 + 0) * MTBL + ivn.x];
            g1 = tbl[(q * 4 + 1) * MTBL + ivn.y];
            g2 = tbl[(q * 4 + 2) * MTBL + ivn.z];
            g3 = tbl[(q * 4 + 3) * MTBL + ivn.w];
        }

#pragma unroll
        for (int t = 0; t < 4; ++t) {
            uint2 pk;
            pk.x = pack2bf(fmaxf(acc[t][0], 0.f), fmaxf(acc[t][1], 0.f));
            pk.y = pack2bf(fmaxf(acc[t][2], 0.f), fmaxf(acc[t][3], 0.f));
            *(uint2*)(hrow + t * 16 + q * 4) = pk;
        }
        Bh0 = *(const short8*)(hrow + q * 8);
        Bh1 = *(const short8*)(hrow + 32 + q * 8);

#pragma unroll
        for (int t = 0; t < 4; ++t) {
            acc[t] = __builtin_amdgcn_mfma_f32_16x16x32_bf16(A3[t][0], Bh0, C3[t], 0, 0, 0);
            acc[t] = __builtin_amdgcn_mfma_f32_16x16x32_bf16(A3[t][1], Bh1, acc[t], 0, 0, 0);
        }

#pragma unroll
        for (int t = 0; t < 4; ++t) {
            uint2 pk;
            pk.x = pack2bf(fmaxf(acc[t][0], 0.f), fmaxf(acc[t][1], 0.f));
            pk.y = pack2bf(fmaxf(acc[t][2], 0.f), fmaxf(acc[t][3], 0.f));
            *(uint2*)(hrow + t * 16 + q * 4) = pk;
        }
        Bh0 = *(const short8*)(hrow + q * 8);
        Bh1 = *(const short8*)(hrow + 32 + q * 8);

        floatx4 o;
        o = __builtin_amdgcn_mfma_f32_16x16x32_bf16(A4[0], Bh0, C4, 0, 0, 0);
        o = __builtin_amdgcn_mfma_f32_16x16x32_bf16(A4[1], Bh1, o, 0, 0, 0);

        if (q == 0) {
            const int pn = pbase + m;
            out[pn * 3 + 0] = o[0];
            out[pn * 3 + 1] = o[1];
            out[pn * 3 + 2] = o[2];
        }
    }
}

extern "C" void kernel_launch(void* const* d_in, const int* in_sizes, int n_in,
                              void* d_out, int out_size, void* d_ws, size_t ws_size,
                              hipStream_t stream) {
    const int*   idx    = (const int*)d_in[0];
    const float* tables = (const float*)d_in[1];
    const float* W1 = (const float*)d_in[2];
    const float* b1 = (const float*)d_in[3];
    const float* W2 = (const float*)d_in[4];
    const float* b2 = (const float*)d_in[5];
    const float* W3 = (const float*)d_in[6];
    const float* b3 = (const float*)d_in[7];
    const float* W4 = (const float*)d_in[8];
    const float* b4 = (const float*)d_in[9];
    float* out = (float*)d_out;

    const int N = in_sizes[0] / 16;            // points (2,097,152)
    const int total_tiles = N / 16;

    const size_t idxT_bytes = (size_t)16 * N * 4;           // 128 MiB
    const size_t xU_bytes   = (size_t)16 * N * 4;           // 128 MiB
    const size_t tblC_bytes = (size_t)16 * MTBL * 4;        // 32 MiB
    const size_t need = idxT_bytes + xU_bytes + tblC_bytes;

    if (ws_size >= need) {
        int*          idxT = (int*)d_ws;
        unsigned int* xU   = (unsigned int*)((char*)d_ws + idxT_bytes);
        unsigned int* tblC = (unsigned int*)((char*)d_ws + idxT_bytes + xU_bytes);

        // P: fused transpose + compress (plain loads, NT stores)
        const int tblocks = N / 1024;
        const int cblocks = (16 * MTBL) / 1024;
        ngp_prep<<<tblocks + cblocks, 256, 0, stream>>>(
            idx, idxT, (const floatx4*)tables, tblC, N);
        // B: both gather phases in one launch (phase = bit 11)
        const int iters = (N >> 8) >> 11;   // points/block / 2048 = 4
        ngp_gather<<<4096, 256, 0, stream>>>(idxT, tblC, xU, N, iters);
        // C: MFMA MLP (lane-local transitions, 2-tile ILP, 24 KB LDS, 4096 blocks)
        const int blocks = 4096;
        const int tiles_per_wave = total_tiles / (blocks * 4);   // 8
        ngp_mlp<<<blocks, 256, 0, stream>>>(xU, W1, b1, W2, b2, W3, b3, W4, b4,
                                            out, N, tiles_per_wave);
    } else {
        const int blocks = 2048;
        const int tiles_per_wave = total_tiles / (blocks * 4);
        ngp_fused<<<blocks, 256, 0, stream>>>(idx, tables, W1, b1, W2, b2, W3, b3,
                                              W4, b4, out, tiles_per_wave);
    }
}

// Round 7
// 567.499 us; speedup vs baseline: 1.3389x; 1.0382x over previous
//
#include <hip/hip_runtime.h>
#include <hip/hip_bf16.h>

typedef __attribute__((ext_vector_type(8))) short short8;
typedef __attribute__((ext_vector_type(4))) float floatx4;
typedef __attribute__((ext_vector_type(4))) int int4v;
typedef __attribute__((ext_vector_type(4))) unsigned int uint4v;

#define MTBL 524288
#define HSTRIDE 72   // fallback kernel only

union U4S8 { uint4v u; short8 s; };

// fp32 -> bf16 round-to-nearest (weight preamble / prep kernels)
static __device__ __forceinline__ unsigned int pack2bf(float a, float b) {
    union { float f; unsigned int u; } x, y;
    x.f = a; y.f = b;
    unsigned int lo = (x.u + 0x8000u) >> 16;
    unsigned int hi = (y.u + 0x8000u) & 0xFFFF0000u;
    return lo | hi;
}
static __device__ __forceinline__ short bf1(float a) {
    union { float f; unsigned int u; } x;
    x.f = a;
    return (short)((x.u + 0x8000u) >> 16);
}

// relu + bf16-pack two acc registers into one MFMA B-fragment (8 bf16).
// __float22bfloat162_rn lowers to v_cvt_pk_bf16_f32 (1 instr / 2 values).
static __device__ __forceinline__ short8 relu_pack(floatx4 a, floatx4 b) {
    union { __hip_bfloat162 h2[4]; short8 s; } r;
    r.h2[0] = __float22bfloat162_rn(make_float2(fmaxf(a[0], 0.f), fmaxf(a[1], 0.f)));
    r.h2[1] = __float22bfloat162_rn(make_float2(fmaxf(a[2], 0.f), fmaxf(a[3], 0.f)));
    r.h2[2] = __float22bfloat162_rn(make_float2(fmaxf(b[0], 0.f), fmaxf(b[1], 0.f)));
    r.h2[3] = __float22bfloat162_rn(make_float2(fmaxf(b[2], 0.f), fmaxf(b[3], 0.f)));
    return r.s;
}

// one full MLP chain for a 16-point tile, lane-local transitions.
// Layout trick (R1): A-fragment t covers permuted output columns
//   c_t(p) = 32*(t>>1) + 4*(t&1) + 8*(p>>2) + (p&3)
// so lane (q,m) holds h[32*(t>>1)+4*(t&1)+8q+r] in acc[t][r] and the next
// layer's B-fragment is relu_pack of the SAME lane's accumulators.
static __device__ __forceinline__ floatx4 mlp_chain(
    uint4v cur,
    const short8 (&A1)[4], const short8 (&A2)[4][2], const short8 (&A3)[4][2],
    const short8 (&A4)[2],
    const floatx4 (&C1)[4], const floatx4 (&C2)[4], const floatx4 (&C3)[4],
    floatx4 C4)
{
    U4S8 bx; bx.u = cur;
    const short8 Bx = bx.s;

    floatx4 h[4];
#pragma unroll
    for (int t = 0; t < 4; ++t)
        h[t] = __builtin_amdgcn_mfma_f32_16x16x32_bf16(A1[t], Bx, C1[t], 0, 0, 0);
    short8 B0 = relu_pack(h[0], h[1]);
    short8 B1 = relu_pack(h[2], h[3]);

#pragma unroll
    for (int t = 0; t < 4; ++t) {
        h[t] = __builtin_amdgcn_mfma_f32_16x16x32_bf16(A2[t][0], B0, C2[t], 0, 0, 0);
        h[t] = __builtin_amdgcn_mfma_f32_16x16x32_bf16(A2[t][1], B1, h[t], 0, 0, 0);
    }
    B0 = relu_pack(h[0], h[1]);
    B1 = relu_pack(h[2], h[3]);

#pragma unroll
    for (int t = 0; t < 4; ++t) {
        h[t] = __builtin_amdgcn_mfma_f32_16x16x32_bf16(A3[t][0], B0, C3[t], 0, 0, 0);
        h[t] = __builtin_amdgcn_mfma_f32_16x16x32_bf16(A3[t][1], B1, h[t], 0, 0, 0);
    }
    B0 = relu_pack(h[0], h[1]);
    B1 = relu_pack(h[2], h[3]);

    floatx4 o;
    o = __builtin_amdgcn_mfma_f32_16x16x32_bf16(A4[0], B0, C4, 0, 0, 0);
    o = __builtin_amdgcn_mfma_f32_16x16x32_bf16(A4[1], B1, o, 0, 0, 0);
    return o;
}

// ---------------- Kernel P: fused prep ----------------
// blocks [0, N/1024):           transpose idx [N][16] -> idxT [16][N]
// blocks [N/1024, +16M/1024):   compress tables fp32 [16*M][2] -> packed bf16
// Plain (cached) loads; NT only on the write-once stores (R6-verified).
__global__ __launch_bounds__(256) void ngp_prep(
    const int* __restrict__ idx, int* __restrict__ idxT,
    const floatx4* __restrict__ tab4, unsigned int* __restrict__ tblC, int N)
{
    const int tblocks = N >> 10;
    if ((int)blockIdx.x < tblocks) {
        const int t  = blockIdx.x * 256 + threadIdx.x;
        const int p0 = t * 4;
        const int4v* rows = (const int4v*)idx;
        int4v r[4][4];
#pragma unroll
        for (int p = 0; p < 4; ++p)
#pragma unroll
            for (int c = 0; c < 4; ++c)
                r[p][c] = rows[(size_t)(p0 + p) * 4 + c];
#pragma unroll
        for (int c = 0; c < 4; ++c)
#pragma unroll
            for (int k = 0; k < 4; ++k) {
                const int h = c * 4 + k;
                int4v w;
                w[0] = r[0][c][k]; w[1] = r[1][c][k]; w[2] = r[2][c][k]; w[3] = r[3][c][k];
                __builtin_nontemporal_store(w, (int4v*)(idxT + (size_t)h * N + p0));
            }
    } else {
        const int t = (blockIdx.x - tblocks) * 256 + threadIdx.x;
        floatx4 a = tab4[(size_t)2 * t];
        floatx4 b = tab4[(size_t)2 * t + 1];
        uint4v w;
        w[0] = pack2bf(a[0], a[1]);
        w[1] = pack2bf(a[2], a[3]);
        w[2] = pack2bf(b[0], b[1]);
        w[3] = pack2bf(b[2], b[3]);
        __builtin_nontemporal_store(w, (uint4v*)(tblC + (size_t)4 * t));
    }
}

// ---------------- Kernel B: one-head-per-XCD gather, both phases ----------------
// 4096 blocks: phase = bit 11 of blockIdx; XCD = blk & 7; per-XCD live table
// slice 2 MiB.  idxT/xU accesses are NT (no-allocate) so the table keeps L2.
// COALESCED TILING (R7): each thread owns 4 CONTIGUOUS points per chunk
// (p = tid*4), two chunks 1024 points apart per iteration.  Every idx load
// and xU store is lane-contiguous (1 KB/instruction, full 32B sectors).
// The previous 8-points-per-thread layout had lanes writing 16B at 32B
// stride -> half-filled sectors committed twice = 252 MB WRITE_SIZE for a
// 128 MB output (R6 counters); those extra sector ops competed with the
// random table gathers for L2 request slots.
__global__ __launch_bounds__(256) void ngp_gather(
    const int* __restrict__ idxT, const unsigned int* __restrict__ tblC,
    unsigned int* __restrict__ xU, int N, int iters)
{
    const int phase = (blockIdx.x >> 11) & 1;
    const int blk   = blockIdx.x & 2047;
    const int h     = ((blk & 7) << 1) | phase;
    const int slot  = blk >> 3;                       // 0..255
    const int* __restrict__ ih = idxT + (size_t)h * N;
    const unsigned int* __restrict__ th = tblC + (size_t)h * MTBL;
    unsigned int* __restrict__ xh = xU + (size_t)h * N;

    int p = slot * (N >> 8) + (threadIdx.x << 2);     // 4 contiguous points/chunk
    int4v iv0 = __builtin_nontemporal_load((const int4v*)(ih + p));
    int4v iv1 = __builtin_nontemporal_load((const int4v*)(ih + p + 1024));
    for (int it = 0; it < iters; ++it) {
        int4v nv0 = iv0, nv1 = iv1;
        if (it + 1 < iters) {
            nv0 = __builtin_nontemporal_load((const int4v*)(ih + p + 2048));
            nv1 = __builtin_nontemporal_load((const int4v*)(ih + p + 3072));
        }
        uint4v w0, w1;
        w0[0] = th[iv0[0]]; w0[1] = th[iv0[1]]; w0[2] = th[iv0[2]]; w0[3] = th[iv0[3]];
        w1[0] = th[iv1[0]]; w1[1] = th[iv1[1]]; w1[2] = th[iv1[2]]; w1[3] = th[iv1[3]];
        __builtin_nontemporal_store(w0, (uint4v*)(xh + p));
        __builtin_nontemporal_store(w1, (uint4v*)(xh + p + 1024));
        iv0 = nv0; iv1 = nv1;
        p += 2048;
    }
}

// ---------------- Kernel C: MFMA MLP on contiguous xU ----------------
// Lane-local layer transitions (no LDS in loop), 2 independent tiles per
// iteration, two-stage 24 KB weight staging, 4096 blocks (tiles_per_wave=8).
// launch_bounds (256,2): (256,4) forced VGPR=64 and spilled (R0 post-mortem).
__global__ __launch_bounds__(256, 2) void ngp_mlp(
    const unsigned int* __restrict__ xU,
    const float* __restrict__ W1, const float* __restrict__ b1,
    const float* __restrict__ W2, const float* __restrict__ b2,
    const float* __restrict__ W3, const float* __restrict__ b3,
    const float* __restrict__ W4, const float* __restrict__ b4,
    float* __restrict__ out, int N, int tiles_per_wave)
{
    __shared__ float sW[6144];   // 24 KB, reused across 2 staging stages

    const int tid  = threadIdx.x;
    const int wave = tid >> 6;
    const int lane = tid & 63;
    const int q = lane >> 4;
    const int m = lane & 15;

    int ct[4];
#pragma unroll
    for (int t = 0; t < 4; ++t)
        ct[t] = 32 * (t >> 1) + 4 * (t & 1) + 8 * (m >> 2) + (m & 3);

    short8 A1[4], A2[4][2], A3[4][2], A4[2];
    floatx4 C1[4], C2[4], C3[4], C4;

    // ---- stage A: W1 (2048) + W2 (4096) ----
    for (int i = tid; i < 2048; i += 256) sW[i] = W1[i];
    for (int i = tid; i < 4096; i += 256) sW[2048 + i] = W2[i];
    __syncthreads();
#pragma unroll
    for (int t = 0; t < 4; ++t) {
        short8 a;
#pragma unroll
        for (int j = 0; j < 8; ++j)
            a[j] = bf1(sW[(q * 8 + j) * 64 + ct[t]]);
        A1[t] = a;
    }
#pragma unroll
    for (int t = 0; t < 4; ++t)
#pragma unroll
        for (int c = 0; c < 2; ++c) {
            short8 a;
#pragma unroll
            for (int j = 0; j < 8; ++j)
                a[j] = bf1(sW[2048 + (c * 32 + q * 8 + j) * 64 + ct[t]]);
            A2[t][c] = a;
        }
    __syncthreads();

    // ---- stage B: W3 (4096) + W4 (192) + biases (195) ----
    for (int i = tid; i < 4096; i += 256) sW[i] = W3[i];
    if (tid < 192) sW[4096 + tid] = W4[tid];
    if (tid < 64)       sW[4288 + tid] = b1[tid];
    else if (tid < 128) sW[4288 + tid] = b2[tid - 64];
    else if (tid < 192) sW[4288 + tid] = b3[tid - 128];
    else if (tid < 195) sW[4288 + tid] = b4[tid - 192];
    __syncthreads();
#pragma unroll
    for (int t = 0; t < 4; ++t)
#pragma unroll
        for (int c = 0; c < 2; ++c) {
            short8 a;
#pragma unroll
            for (int j = 0; j < 8; ++j)
                a[j] = bf1(sW[(c * 32 + q * 8 + j) * 64 + ct[t]]);
            A3[t][c] = a;
        }
#pragma unroll
    for (int c = 0; c < 2; ++c) {
        short8 a;
#pragma unroll
        for (int j = 0; j < 8; ++j)
            a[j] = (m < 3) ? bf1(sW[4096 + (c * 32 + q * 8 + j) * 3 + m]) : (short)0;
        A4[c] = a;
    }
#pragma unroll
    for (int t = 0; t < 4; ++t) {
        const int bi = 32 * (t >> 1) + 4 * (t & 1) + 8 * q;   // permuted bias base
#pragma unroll
        for (int r = 0; r < 4; ++r) {
            C1[t][r] = sW[4288 + bi + r];
            C2[t][r] = sW[4288 + 64 + bi + r];
            C3[t][r] = sW[4288 + 128 + bi + r];
        }
    }
#pragma unroll
    for (int r = 0; r < 4; ++r)
        C4[r] = (q == 0 && r < 3) ? sW[4288 + 192 + r] : 0.0f;

    const int gw = blockIdx.x * 4 + wave;
    const int tile0 = gw * tiles_per_wave;
    const int iters = tiles_per_wave >> 1;    // 2 tiles per iteration

    const unsigned int* xr = xU + (size_t)(q * 4) * N + m;

    #define XLD(tile, c) __builtin_nontemporal_load(&xr[(size_t)(c) * N + (tile) * 16])

    uint4v curA, curB;
    {
        curA[0] = XLD(tile0, 0);     curA[1] = XLD(tile0, 1);
        curA[2] = XLD(tile0, 2);     curA[3] = XLD(tile0, 3);
        curB[0] = XLD(tile0 + 1, 0); curB[1] = XLD(tile0 + 1, 1);
        curB[2] = XLD(tile0 + 1, 2); curB[3] = XLD(tile0 + 1, 3);
    }

    for (int k = 0; k < iters; ++k) {
        const int pbaseA = (tile0 + 2 * k) * 16;
        const bool more = (k + 1) < iters;

        uint4v nxtA = curA, nxtB = curB;
        if (more) {
            const int tn = tile0 + 2 * k + 2;
            nxtA[0] = XLD(tn, 0);     nxtA[1] = XLD(tn, 1);
            nxtA[2] = XLD(tn, 2);     nxtA[3] = XLD(tn, 3);
            nxtB[0] = XLD(tn + 1, 0); nxtB[1] = XLD(tn + 1, 1);
            nxtB[2] = XLD(tn + 1, 2); nxtB[3] = XLD(tn + 1, 3);
        }

        floatx4 oA = mlp_chain(curA, A1, A2, A3, A4, C1, C2, C3, C4);
        floatx4 oB = mlp_chain(curB, A1, A2, A3, A4, C1, C2, C3, C4);

        if (q == 0) {
            const int pA = pbaseA + m;
            __builtin_nontemporal_store(oA[0], out + pA * 3 + 0);
            __builtin_nontemporal_store(oA[1], out + pA * 3 + 1);
            __builtin_nontemporal_store(oA[2], out + pA * 3 + 2);
            const int pB = pA + 16;
            __builtin_nontemporal_store(oB[0], out + pB * 3 + 0);
            __builtin_nontemporal_store(oB[1], out + pB * 3 + 1);
            __builtin_nontemporal_store(oB[2], out + pB * 3 + 2);
        }

        curA = nxtA;
        curB = nxtB;
    }
    #undef XLD
}

// ---------------- Fallback: fused kernel without workspace ----------------
__global__ __launch_bounds__(256, 2) void ngp_fused(
    const int* __restrict__ idx,
    const float* __restrict__ tables,
    const float* __restrict__ W1, const float* __restrict__ b1,
    const float* __restrict__ W2, const float* __restrict__ b2,
    const float* __restrict__ W3, const float* __restrict__ b3,
    const float* __restrict__ W4, const float* __restrict__ b4,
    float* __restrict__ out, int tiles_per_wave)
{
    __shared__ float sW1[2048];
    __shared__ float sW2[4096];
    __shared__ float sW3[4096];
    __shared__ float sW4[192];
    __shared__ float sB[200];
    __shared__ __hip_bfloat16 sH[4][16 * HSTRIDE];

    const int tid = threadIdx.x;
    for (int i = tid; i < 2048; i += 256) sW1[i] = W1[i];
    for (int i = tid; i < 4096; i += 256) sW2[i] = W2[i];
    for (int i = tid; i < 4096; i += 256) sW3[i] = W3[i];
    if (tid < 192) sW4[tid] = W4[tid];
    if (tid < 64)       sB[tid] = b1[tid];
    else if (tid < 128) sB[tid] = b2[tid - 64];
    else if (tid < 192) sB[tid] = b3[tid - 128];
    else if (tid < 195) sB[tid] = b4[tid - 192];
    __syncthreads();

    const int wave = tid >> 6;
    const int lane = tid & 63;
    const int q = lane >> 4;
    const int m = lane & 15;

    short8 A1[4], A2[4][2], A3[4][2], A4[2];
#pragma unroll
    for (int t = 0; t < 4; ++t) {
        short8 a;
#pragma unroll
        for (int j = 0; j < 8; ++j)
            a[j] = bf1(sW1[(q * 8 + j) * 64 + t * 16 + m]);
        A1[t] = a;
    }
#pragma unroll
    for (int t = 0; t < 4; ++t)
#pragma unroll
        for (int c = 0; c < 2; ++c) {
            short8 a, a3;
#pragma unroll
            for (int j = 0; j < 8; ++j) {
                a[j]  = bf1(sW2[(c * 32 + q * 8 + j) * 64 + t * 16 + m]);
                a3[j] = bf1(sW3[(c * 32 + q * 8 + j) * 64 + t * 16 + m]);
            }
            A2[t][c] = a;
            A3[t][c] = a3;
        }
#pragma unroll
    for (int c = 0; c < 2; ++c) {
        short8 a;
#pragma unroll
        for (int j = 0; j < 8; ++j)
            a[j] = (m < 3) ? bf1(sW4[(c * 32 + q * 8 + j) * 3 + m]) : (short)0;
        A4[c] = a;
    }

    floatx4 C1[4], C2[4], C3[4], C4;
#pragma unroll
    for (int t = 0; t < 4; ++t)
#pragma unroll
        for (int r = 0; r < 4; ++r) {
            C1[t][r] = sB[t * 16 + q * 4 + r];
            C2[t][r] = sB[64 + t * 16 + q * 4 + r];
            C3[t][r] = sB[128 + t * 16 + q * 4 + r];
        }
#pragma unroll
    for (int r = 0; r < 4; ++r)
        C4[r] = (q == 0 && r < 3) ? sB[192 + r] : 0.0f;

    __hip_bfloat16* hrow = &sH[wave][m * HSTRIDE];
    const int4*   idx4 = (const int4*)idx;
    const float2* tbl  = (const float2*)tables;

    const int gw = blockIdx.x * 4 + wave;
    const int tile0 = gw * tiles_per_wave;

    int4 iv = idx4[(tile0 * 16 + m) * 4 + q];
    float2 g0 = tbl[(q * 4 + 0) * MTBL + iv.x];
    float2 g1 = tbl[(q * 4 + 1) * MTBL + iv.y];
    float2 g2 = tbl[(q * 4 + 2) * MTBL + iv.z];
    float2 g3 = tbl[(q * 4 + 3) * MTBL + iv.w];

    for (int it = 0; it < tiles_per_wave; ++it) {
        const int pbase = (tile0 + it) * 16;
        const bool more = (it + 1) < tiles_per_wave;

        short8 Bx;
        {
            unsigned int p0 = pack2bf(g0.x, g0.y);
            unsigned int p1 = pack2bf(g1.x, g1.y);
            unsigned int p2 = pack2bf(g2.x, g2.y);
            unsigned int p3 = pack2bf(g3.x, g3.y);
            Bx[0] = (short)(p0 & 0xFFFF); Bx[1] = (short)(p0 >> 16);
            Bx[2] = (short)(p1 & 0xFFFF); Bx[3] = (short)(p1 >> 16);
            Bx[4] = (short)(p2 & 0xFFFF); Bx[5] = (short)(p2 >> 16);
            Bx[6] = (short)(p3 & 0xFFFF); Bx[7] = (short)(p3 >> 16);
        }

        int4 ivn;
        if (more) ivn = idx4[((pbase + 16) + m) * 4 + q];

        floatx4 acc[4];
#pragma unroll
        for (int t = 0; t < 4; ++t)
            acc[t] = __builtin_amdgcn_mfma_f32_16x16x32_bf16(A1[t], Bx, C1[t], 0, 0, 0);

#pragma unroll
        for (int t = 0; t < 4; ++t) {
            uint2 pk;
            pk.x = pack2bf(fmaxf(acc[t][0], 0.f), fmaxf(acc[t][1], 0.f));
            pk.y = pack2bf(fmaxf(acc[t][2], 0.f), fmaxf(acc[t][3], 0.f));
            *(uint2*)(hrow + t * 16 + q * 4) = pk;
        }
        short8 Bh0 = *(const short8*)(hrow + q * 8);
        short8 Bh1 = *(const short8*)(hrow + 32 + q * 8);

#pragma unroll
        for (int t = 0; t < 4; ++t) {
            acc[t] = __builtin_amdgcn_mfma_f32_16x16x32_bf16(A2[t][0], Bh0, C2[t], 0, 0, 0);
            acc[t] = __builtin_amdgcn_mfma_f32_16x16x32_bf16(A2[t][1], Bh1, acc[t], 0, 0, 0);
        }

        if (more) {
            g0 = tbl[(q * 4 + 0) * MTBL + ivn.x];
            g1 = tbl[(q * 4 + 1) * MTBL + ivn.y];
            g2 = tbl[(q * 4 + 2) * MTBL + ivn.z];
            g3 = tbl[(q * 4 + 3) * MTBL + ivn.w];
        }

#pragma unroll
        for (int t = 0; t < 4; ++t) {
            uint2 pk;
            pk.x = pack2bf(fmaxf(acc[t][0], 0.f), fmaxf(acc[t][1], 0.f));
            pk.y = pack2bf(fmaxf(acc[t][2], 0.f), fmaxf(acc[t][3], 0.f));
            *(uint2*)(hrow + t * 16 + q * 4) = pk;
        }
        Bh0 = *(const short8*)(hrow + q * 8);
        Bh1 = *(const short8*)(hrow + 32 + q * 8);

#pragma unroll
        for (int t = 0; t < 4; ++t) {
            acc[t] = __builtin_amdgcn_mfma_f32_16x16x32_bf16(A3[t][0], Bh0, C3[t], 0, 0, 0);
            acc[t] = __builtin_amdgcn_mfma_f32_16x16x32_bf16(A3[t][1], Bh1, acc[t], 0, 0, 0);
        }

#pragma unroll
        for (int t = 0; t < 4; ++t) {
            uint2 pk;
            pk.x = pack2bf(fmaxf(acc[t][0], 0.f), fmaxf(acc[t][1], 0.f));
            pk.y = pack2bf(fmaxf(acc[t][2], 0.f), fmaxf(acc[t][3], 0.f));
            *(uint2*)(hrow + t * 16 + q * 4) = pk;
        }
        Bh0 = *(const short8*)(hrow + q * 8);
        Bh1 = *(const short8*)(hrow + 32 + q * 8);

        floatx4 o;
        o = __builtin_amdgcn_mfma_f32_16x16x32_bf16(A4[0], Bh0, C4, 0, 0, 0);
        o = __builtin_amdgcn_mfma_f32_16x16x32_bf16(A4[1], Bh1, o, 0, 0, 0);

        if (q == 0) {
            const int pn = pbase + m;
            out[pn * 3 + 0] = o[0];
            out[pn * 3 + 1] = o[1];
            out[pn * 3 + 2] = o[2];
        }
    }
}

extern "C" void kernel_launch(void* const* d_in, const int* in_sizes, int n_in,
                              void* d_out, int out_size, void* d_ws, size_t ws_size,
                              hipStream_t stream) {
    const int*   idx    = (const int*)d_in[0];
    const float* tables = (const float*)d_in[1];
    const float* W1 = (const float*)d_in[2];
    const float* b1 = (const float*)d_in[3];
    const float* W2 = (const float*)d_in[4];
    const float* b2 = (const float*)d_in[5];
    const float* W3 = (const float*)d_in[6];
    const float* b3 = (const float*)d_in[7];
    const float* W4 = (const float*)d_in[8];
    const float* b4 = (const float*)d_in[9];
    float* out = (float*)d_out;

    const int N = in_sizes[0] / 16;            // points (2,097,152)
    const int total_tiles = N / 16;

    const size_t idxT_bytes = (size_t)16 * N * 4;           // 128 MiB
    const size_t xU_bytes   = (size_t)16 * N * 4;           // 128 MiB
    const size_t tblC_bytes = (size_t)16 * MTBL * 4;        // 32 MiB
    const size_t need = idxT_bytes + xU_bytes + tblC_bytes;

    if (ws_size >= need) {
        int*          idxT = (int*)d_ws;
        unsigned int* xU   = (unsigned int*)((char*)d_ws + idxT_bytes);
        unsigned int* tblC = (unsigned int*)((char*)d_ws + idxT_bytes + xU_bytes);

        // P: fused transpose + compress (plain loads, NT stores)
        const int tblocks = N / 1024;
        const int cblocks = (16 * MTBL) / 1024;
        ngp_prep<<<tblocks + cblocks, 256, 0, stream>>>(
            idx, idxT, (const floatx4*)tables, tblC, N);
        // B: both gather phases in one launch (phase = bit 11), coalesced tiling
        const int iters = (N >> 8) >> 11;   // 4
        ngp_gather<<<4096, 256, 0, stream>>>(idxT, tblC, xU, N, iters);
        // C: MFMA MLP (lane-local transitions, 2-tile ILP, 24 KB LDS, 4096 blocks)
        const int blocks = 4096;
        const int tiles_per_wave = total_tiles / (blocks * 4);   // 8
        ngp_mlp<<<blocks, 256, 0, stream>>>(xU, W1, b1, W2, b2, W3, b3, W4, b4,
                                            out, N, tiles_per_wave);
    } else {
        const int blocks = 2048;
        const int tiles_per_wave = total_tiles / (blocks * 4);
        ngp_fused<<<blocks, 256, 0, stream>>>(idx, tables, W1, b1, W2, b2, W3, b3,
                                              W4, b4, out, tiles_per_wave);
    }
}

// Round 8
// 541.209 us; speedup vs baseline: 1.4040x; 1.0486x over previous
//
#include <hip/hip_runtime.h>
#include <hip/hip_bf16.h>

typedef __attribute__((ext_vector_type(8))) short short8;
typedef __attribute__((ext_vector_type(4))) float floatx4;
typedef __attribute__((ext_vector_type(4))) int int4v;
typedef __attribute__((ext_vector_type(4))) unsigned int uint4v;

#define MTBL 524288
#define HSTRIDE 72   // fallback kernel only

union U4S8 { uint4v u; short8 s; };

// fp32 -> bf16 round-to-nearest (weight preamble / prep kernels)
static __device__ __forceinline__ unsigned int pack2bf(float a, float b) {
    union { float f; unsigned int u; } x, y;
    x.f = a; y.f = b;
    unsigned int lo = (x.u + 0x8000u) >> 16;
    unsigned int hi = (y.u + 0x8000u) & 0xFFFF0000u;
    return lo | hi;
}
static __device__ __forceinline__ short bf1(float a) {
    union { float f; unsigned int u; } x;
    x.f = a;
    return (short)((x.u + 0x8000u) >> 16);
}

// relu + bf16-pack two acc registers into one MFMA B-fragment (8 bf16).
// __float22bfloat162_rn lowers to v_cvt_pk_bf16_f32 (1 instr / 2 values).
static __device__ __forceinline__ short8 relu_pack(floatx4 a, floatx4 b) {
    union { __hip_bfloat162 h2[4]; short8 s; } r;
    r.h2[0] = __float22bfloat162_rn(make_float2(fmaxf(a[0], 0.f), fmaxf(a[1], 0.f)));
    r.h2[1] = __float22bfloat162_rn(make_float2(fmaxf(a[2], 0.f), fmaxf(a[3], 0.f)));
    r.h2[2] = __float22bfloat162_rn(make_float2(fmaxf(b[0], 0.f), fmaxf(b[1], 0.f)));
    r.h2[3] = __float22bfloat162_rn(make_float2(fmaxf(b[2], 0.f), fmaxf(b[3], 0.f)));
    return r.s;
}

// one full MLP chain for a 16-point tile, lane-local transitions.
// Layout trick (R1): A-fragment t covers permuted output columns
//   c_t(p) = 32*(t>>1) + 4*(t&1) + 8*(p>>2) + (p&3)
// so lane (q,m) holds h[32*(t>>1)+4*(t&1)+8q+r] in acc[t][r] and the next
// layer's B-fragment is relu_pack of the SAME lane's accumulators.
static __device__ __forceinline__ floatx4 mlp_chain(
    uint4v cur,
    const short8 (&A1)[4], const short8 (&A2)[4][2], const short8 (&A3)[4][2],
    const short8 (&A4)[2],
    const floatx4 (&C1)[4], const floatx4 (&C2)[4], const floatx4 (&C3)[4],
    floatx4 C4)
{
    U4S8 bx; bx.u = cur;
    const short8 Bx = bx.s;

    floatx4 h[4];
#pragma unroll
    for (int t = 0; t < 4; ++t)
        h[t] = __builtin_amdgcn_mfma_f32_16x16x32_bf16(A1[t], Bx, C1[t], 0, 0, 0);
    short8 B0 = relu_pack(h[0], h[1]);
    short8 B1 = relu_pack(h[2], h[3]);

#pragma unroll
    for (int t = 0; t < 4; ++t) {
        h[t] = __builtin_amdgcn_mfma_f32_16x16x32_bf16(A2[t][0], B0, C2[t], 0, 0, 0);
        h[t] = __builtin_amdgcn_mfma_f32_16x16x32_bf16(A2[t][1], B1, h[t], 0, 0, 0);
    }
    B0 = relu_pack(h[0], h[1]);
    B1 = relu_pack(h[2], h[3]);

#pragma unroll
    for (int t = 0; t < 4; ++t) {
        h[t] = __builtin_amdgcn_mfma_f32_16x16x32_bf16(A3[t][0], B0, C3[t], 0, 0, 0);
        h[t] = __builtin_amdgcn_mfma_f32_16x16x32_bf16(A3[t][1], B1, h[t], 0, 0, 0);
    }
    B0 = relu_pack(h[0], h[1]);
    B1 = relu_pack(h[2], h[3]);

    floatx4 o;
    o = __builtin_amdgcn_mfma_f32_16x16x32_bf16(A4[0], B0, C4, 0, 0, 0);
    o = __builtin_amdgcn_mfma_f32_16x16x32_bf16(A4[1], B1, o, 0, 0, 0);
    return o;
}

// ---------------- Kernel P: fused prep ----------------
// blocks [0, N/1024):           transpose idx [N][16] -> idxT [16][N]
// blocks [N/1024, +16M/1024):   compress tables fp32 [16*M][2] -> packed bf16
// Plain (cached) loads; NT only on the write-once stores (R6-verified).
__global__ __launch_bounds__(256) void ngp_prep(
    const int* __restrict__ idx, int* __restrict__ idxT,
    const floatx4* __restrict__ tab4, unsigned int* __restrict__ tblC, int N)
{
    const int tblocks = N >> 10;
    if ((int)blockIdx.x < tblocks) {
        const int t  = blockIdx.x * 256 + threadIdx.x;
        const int p0 = t * 4;
        const int4v* rows = (const int4v*)idx;
        int4v r[4][4];
#pragma unroll
        for (int p = 0; p < 4; ++p)
#pragma unroll
            for (int c = 0; c < 4; ++c)
                r[p][c] = rows[(size_t)(p0 + p) * 4 + c];
#pragma unroll
        for (int c = 0; c < 4; ++c)
#pragma unroll
            for (int k = 0; k < 4; ++k) {
                const int h = c * 4 + k;
                int4v w;
                w[0] = r[0][c][k]; w[1] = r[1][c][k]; w[2] = r[2][c][k]; w[3] = r[3][c][k];
                __builtin_nontemporal_store(w, (int4v*)(idxT + (size_t)h * N + p0));
            }
    } else {
        const int t = (blockIdx.x - tblocks) * 256 + threadIdx.x;
        floatx4 a = tab4[(size_t)2 * t];
        floatx4 b = tab4[(size_t)2 * t + 1];
        uint4v w;
        w[0] = pack2bf(a[0], a[1]);
        w[1] = pack2bf(a[2], a[3]);
        w[2] = pack2bf(b[0], b[1]);
        w[3] = pack2bf(b[2], b[3]);
        __builtin_nontemporal_store(w, (uint4v*)(tblC + (size_t)4 * t));
    }
}

// ---------------- Kernel B: one-head-per-XCD gather, both phases ----------------
// 4096 blocks: phase = bit 11 of blockIdx; XCD = blk & 7; per-XCD live table
// slice 2 MiB.  idxT/xU accesses are NT (no-allocate) so the table keeps L2.
// Coalesced tiling (R7-verified: WRITE_SIZE 252->128 MB): 4 contiguous points
// per chunk, two chunks 1024 apart per iteration, idx prefetched 1 iter ahead.
__global__ __launch_bounds__(256) void ngp_gather(
    const int* __restrict__ idxT, const unsigned int* __restrict__ tblC,
    unsigned int* __restrict__ xU, int N, int iters)
{
    const int phase = (blockIdx.x >> 11) & 1;
    const int blk   = blockIdx.x & 2047;
    const int h     = ((blk & 7) << 1) | phase;
    const int slot  = blk >> 3;                       // 0..255
    const int* __restrict__ ih = idxT + (size_t)h * N;
    const unsigned int* __restrict__ th = tblC + (size_t)h * MTBL;
    unsigned int* __restrict__ xh = xU + (size_t)h * N;

    int p = slot * (N >> 8) + (threadIdx.x << 2);     // 4 contiguous points/chunk
    int4v iv0 = __builtin_nontemporal_load((const int4v*)(ih + p));
    int4v iv1 = __builtin_nontemporal_load((const int4v*)(ih + p + 1024));
    for (int it = 0; it < iters; ++it) {
        int4v nv0 = iv0, nv1 = iv1;
        if (it + 1 < iters) {
            nv0 = __builtin_nontemporal_load((const int4v*)(ih + p + 2048));
            nv1 = __builtin_nontemporal_load((const int4v*)(ih + p + 3072));
        }
        uint4v w0, w1;
        w0[0] = th[iv0[0]]; w0[1] = th[iv0[1]]; w0[2] = th[iv0[2]]; w0[3] = th[iv0[3]];
        w1[0] = th[iv1[0]]; w1[1] = th[iv1[1]]; w1[2] = th[iv1[2]]; w1[3] = th[iv1[3]];
        __builtin_nontemporal_store(w0, (uint4v*)(xh + p));
        __builtin_nontemporal_store(w1, (uint4v*)(xh + p + 1024));
        iv0 = nv0; iv1 = nv1;
        p += 2048;
    }
}

// ---------------- Kernel C: MFMA MLP on contiguous xU ----------------
// Lane-local layer transitions (no LDS in loop).  FOUR independent tiles per
// iteration (R8): the chain is latency-bound (R4: MfmaUtil 11-13%, 22 serial
// MFMAs); 2-chain VGPR_Count was 128 => 4 chains fit in ~200 VGPRs, under the
// 256 allowed by (256,2).  All chain arrays indexed by unrolled
// compile-time constants (runtime-indexed ext_vector arrays -> scratch).
// launch_bounds (256,2): (256,4) forced VGPR=64 and spilled (R0 post-mortem).
__global__ __launch_bounds__(256, 2) void ngp_mlp(
    const unsigned int* __restrict__ xU,
    const float* __restrict__ W1, const float* __restrict__ b1,
    const float* __restrict__ W2, const float* __restrict__ b2,
    const float* __restrict__ W3, const float* __restrict__ b3,
    const float* __restrict__ W4, const float* __restrict__ b4,
    float* __restrict__ out, int N, int tiles_per_wave)
{
    __shared__ float sW[6144];   // 24 KB, reused across 2 staging stages

    const int tid  = threadIdx.x;
    const int wave = tid >> 6;
    const int lane = tid & 63;
    const int q = lane >> 4;
    const int m = lane & 15;

    int ct[4];
#pragma unroll
    for (int t = 0; t < 4; ++t)
        ct[t] = 32 * (t >> 1) + 4 * (t & 1) + 8 * (m >> 2) + (m & 3);

    short8 A1[4], A2[4][2], A3[4][2], A4[2];
    floatx4 C1[4], C2[4], C3[4], C4;

    // ---- stage A: W1 (2048) + W2 (4096) ----
    for (int i = tid; i < 2048; i += 256) sW[i] = W1[i];
    for (int i = tid; i < 4096; i += 256) sW[2048 + i] = W2[i];
    __syncthreads();
#pragma unroll
    for (int t = 0; t < 4; ++t) {
        short8 a;
#pragma unroll
        for (int j = 0; j < 8; ++j)
            a[j] = bf1(sW[(q * 8 + j) * 64 + ct[t]]);
        A1[t] = a;
    }
#pragma unroll
    for (int t = 0; t < 4; ++t)
#pragma unroll
        for (int c = 0; c < 2; ++c) {
            short8 a;
#pragma unroll
            for (int j = 0; j < 8; ++j)
                a[j] = bf1(sW[2048 + (c * 32 + q * 8 + j) * 64 + ct[t]]);
            A2[t][c] = a;
        }
    __syncthreads();

    // ---- stage B: W3 (4096) + W4 (192) + biases (195) ----
    for (int i = tid; i < 4096; i += 256) sW[i] = W3[i];
    if (tid < 192) sW[4096 + tid] = W4[tid];
    if (tid < 64)       sW[4288 + tid] = b1[tid];
    else if (tid < 128) sW[4288 + tid] = b2[tid - 64];
    else if (tid < 192) sW[4288 + tid] = b3[tid - 128];
    else if (tid < 195) sW[4288 + tid] = b4[tid - 192];
    __syncthreads();
#pragma unroll
    for (int t = 0; t < 4; ++t)
#pragma unroll
        for (int c = 0; c < 2; ++c) {
            short8 a;
#pragma unroll
            for (int j = 0; j < 8; ++j)
                a[j] = bf1(sW[(c * 32 + q * 8 + j) * 64 + ct[t]]);
            A3[t][c] = a;
        }
#pragma unroll
    for (int c = 0; c < 2; ++c) {
        short8 a;
#pragma unroll
        for (int j = 0; j < 8; ++j)
            a[j] = (m < 3) ? bf1(sW[4096 + (c * 32 + q * 8 + j) * 3 + m]) : (short)0;
        A4[c] = a;
    }
#pragma unroll
    for (int t = 0; t < 4; ++t) {
        const int bi = 32 * (t >> 1) + 4 * (t & 1) + 8 * q;   // permuted bias base
#pragma unroll
        for (int r = 0; r < 4; ++r) {
            C1[t][r] = sW[4288 + bi + r];
            C2[t][r] = sW[4288 + 64 + bi + r];
            C3[t][r] = sW[4288 + 128 + bi + r];
        }
    }
#pragma unroll
    for (int r = 0; r < 4; ++r)
        C4[r] = (q == 0 && r < 3) ? sW[4288 + 192 + r] : 0.0f;

    const int gw = blockIdx.x * 4 + wave;
    const int tile0 = gw * tiles_per_wave;
    const int iters = tiles_per_wave >> 2;    // 4 tiles per iteration

    const unsigned int* xr = xU + (size_t)(q * 4) * N + m;

    #define XLD(tile, c) __builtin_nontemporal_load(&xr[(size_t)(c) * N + (tile) * 16])

    uint4v cur[4];
#pragma unroll
    for (int j = 0; j < 4; ++j) {
        cur[j][0] = XLD(tile0 + j, 0);
        cur[j][1] = XLD(tile0 + j, 1);
        cur[j][2] = XLD(tile0 + j, 2);
        cur[j][3] = XLD(tile0 + j, 3);
    }

    for (int k = 0; k < iters; ++k) {
        const int pbase = (tile0 + 4 * k) * 16;
        const bool more = (k + 1) < iters;

        uint4v nxt[4];
#pragma unroll
        for (int j = 0; j < 4; ++j) nxt[j] = cur[j];
        if (more) {
            const int tn = tile0 + 4 * k + 4;
#pragma unroll
            for (int j = 0; j < 4; ++j) {
                nxt[j][0] = XLD(tn + j, 0);
                nxt[j][1] = XLD(tn + j, 1);
                nxt[j][2] = XLD(tn + j, 2);
                nxt[j][3] = XLD(tn + j, 3);
            }
        }

        // four independent chains; inlined bodies form one block and the
        // scheduler interleaves their MFMAs (latency hiding)
        floatx4 o0 = mlp_chain(cur[0], A1, A2, A3, A4, C1, C2, C3, C4);
        floatx4 o1 = mlp_chain(cur[1], A1, A2, A3, A4, C1, C2, C3, C4);
        floatx4 o2 = mlp_chain(cur[2], A1, A2, A3, A4, C1, C2, C3, C4);
        floatx4 o3 = mlp_chain(cur[3], A1, A2, A3, A4, C1, C2, C3, C4);

        if (q == 0) {
            const int p0 = pbase + m;
            __builtin_nontemporal_store(o0[0], out + p0 * 3 + 0);
            __builtin_nontemporal_store(o0[1], out + p0 * 3 + 1);
            __builtin_nontemporal_store(o0[2], out + p0 * 3 + 2);
            const int p1 = p0 + 16;
            __builtin_nontemporal_store(o1[0], out + p1 * 3 + 0);
            __builtin_nontemporal_store(o1[1], out + p1 * 3 + 1);
            __builtin_nontemporal_store(o1[2], out + p1 * 3 + 2);
            const int p2 = p0 + 32;
            __builtin_nontemporal_store(o2[0], out + p2 * 3 + 0);
            __builtin_nontemporal_store(o2[1], out + p2 * 3 + 1);
            __builtin_nontemporal_store(o2[2], out + p2 * 3 + 2);
            const int p3 = p0 + 48;
            __builtin_nontemporal_store(o3[0], out + p3 * 3 + 0);
            __builtin_nontemporal_store(o3[1], out + p3 * 3 + 1);
            __builtin_nontemporal_store(o3[2], out + p3 * 3 + 2);
        }

#pragma unroll
        for (int j = 0; j < 4; ++j) cur[j] = nxt[j];
    }
    #undef XLD
}

// ---------------- Fallback: fused kernel without workspace ----------------
__global__ __launch_bounds__(256, 2) void ngp_fused(
    const int* __restrict__ idx,
    const float* __restrict__ tables,
    const float* __restrict__ W1, const float* __restrict__ b1,
    const float* __restrict__ W2, const float* __restrict__ b2,
    const float* __restrict__ W3, const float* __restrict__ b3,
    const float* __restrict__ W4, const float* __restrict__ b4,
    float* __restrict__ out, int tiles_per_wave)
{
    __shared__ float sW1[2048];
    __shared__ float sW2[4096];
    __shared__ float sW3[4096];
    __shared__ float sW4[192];
    __shared__ float sB[200];
    __shared__ __hip_bfloat16 sH[4][16 * HSTRIDE];

    const int tid = threadIdx.x;
    for (int i = tid; i < 2048; i += 256) sW1[i] = W1[i];
    for (int i = tid; i < 4096; i += 256) sW2[i] = W2[i];
    for (int i = tid; i < 4096; i += 256) sW3[i] = W3[i];
    if (tid < 192) sW4[tid] = W4[tid];
    if (tid < 64)       sB[tid] = b1[tid];
    else if (tid < 128) sB[tid] = b2[tid - 64];
    else if (tid < 192) sB[tid] = b3[tid - 128];
    else if (tid < 195) sB[tid] = b4[tid - 192];
    __syncthreads();

    const int wave = tid >> 6;
    const int lane = tid & 63;
    const int q = lane >> 4;
    const int m = lane & 15;

    short8 A1[4], A2[4][2], A3[4][2], A4[2];
#pragma unroll
    for (int t = 0; t < 4; ++t) {
        short8 a;
#pragma unroll
        for (int j = 0; j < 8; ++j)
            a[j] = bf1(sW1[(q * 8 + j) * 64 + t * 16 + m]);
        A1[t] = a;
    }
#pragma unroll
    for (int t = 0; t < 4; ++t)
#pragma unroll
        for (int c = 0; c < 2; ++c) {
            short8 a, a3;
#pragma unroll
            for (int j = 0; j < 8; ++j) {
                a[j]  = bf1(sW2[(c * 32 + q * 8 + j) * 64 + t * 16 + m]);
                a3[j] = bf1(sW3[(c * 32 + q * 8 + j) * 64 + t * 16 + m]);
            }
            A2[t][c] = a;
            A3[t][c] = a3;
        }
#pragma unroll
    for (int c = 0; c < 2; ++c) {
        short8 a;
#pragma unroll
        for (int j = 0; j < 8; ++j)
            a[j] = (m < 3) ? bf1(sW4[(c * 32 + q * 8 + j) * 3 + m]) : (short)0;
        A4[c] = a;
    }

    floatx4 C1[4], C2[4], C3[4], C4;
#pragma unroll
    for (int t = 0; t < 4; ++t)
#pragma unroll
        for (int r = 0; r < 4; ++r) {
            C1[t][r] = sB[t * 16 + q * 4 + r];
            C2[t][r] = sB[64 + t * 16 + q * 4 + r];
            C3[t][r] = sB[128 + t * 16 + q * 4 + r];
        }
#pragma unroll
    for (int r = 0; r < 4; ++r)
        C4[r] = (q == 0 && r < 3) ? sB[192 + r] : 0.0f;

    __hip_bfloat16* hrow = &sH[wave][m * HSTRIDE];
    const int4*   idx4 = (const int4*)idx;
    const float2* tbl  = (const float2*)tables;

    const int gw = blockIdx.x * 4 + wave;
    const int tile0 = gw * tiles_per_wave;

    int4 iv = idx4[(tile0 * 16 + m) * 4 + q];
    float2 g0 = tbl[(q * 4 + 0) * MTBL + iv.x];
    float2 g1 = tbl[(q * 4 + 1) * MTBL + iv.y];
    float2 g2 = tbl[(q * 4 + 2) * MTBL + iv.z];
    float2 g3 = tbl[(q * 4 + 3) * MTBL + iv.w];

    for (int it = 0; it < tiles_per_wave; ++it) {
        const int pbase = (tile0 + it) * 16;
        const bool more = (it + 1) < tiles_per_wave;

        short8 Bx;
        {
            unsigned int p0 = pack2bf(g0.x, g0.y);
            unsigned int p1 = pack2bf(g1.x, g1.y);
            unsigned int p2 = pack2bf(g2.x, g2.y);
            unsigned int p3 = pack2bf(g3.x, g3.y);
            Bx[0] = (short)(p0 & 0xFFFF); Bx[1] = (short)(p0 >> 16);
            Bx[2] = (short)(p1 & 0xFFFF); Bx[3] = (short)(p1 >> 16);
            Bx[4] = (short)(p2 & 0xFFFF); Bx[5] = (short)(p2 >> 16);
            Bx[6] = (short)(p3 & 0xFFFF); Bx[7] = (short)(p3 >> 16);
        }

        int4 ivn;
        if (more) ivn = idx4[((pbase + 16) + m) * 4 + q];

        floatx4 acc[4];
#pragma unroll
        for (int t = 0; t < 4; ++t)
            acc[t] = __builtin_amdgcn_mfma_f32_16x16x32_bf16(A1[t], Bx, C1[t], 0, 0, 0);

#pragma unroll
        for (int t = 0; t < 4; ++t) {
            uint2 pk;
            pk.x = pack2bf(fmaxf(acc[t][0], 0.f), fmaxf(acc[t][1], 0.f));
            pk.y = pack2bf(fmaxf(acc[t][2], 0.f), fmaxf(acc[t][3], 0.f));
            *(uint2*)(hrow + t * 16 + q * 4) = pk;
        }
        short8 Bh0 = *(const short8*)(hrow + q * 8);
        short8 Bh1 = *(const short8*)(hrow + 32 + q * 8);

#pragma unroll
        for (int t = 0; t < 4; ++t) {
            acc[t] = __builtin_amdgcn_mfma_f32_16x16x32_bf16(A2[t][0], Bh0, C2[t], 0, 0, 0);
            acc[t] = __builtin_amdgcn_mfma_f32_16x16x32_bf16(A2[t][1], Bh1, acc[t], 0, 0, 0);
        }

        if (more) {
            g0 = tbl[(q * 4 + 0) * MTBL + ivn.x];
            g1 = tbl[(q * 4 + 1) * MTBL + ivn.y];
            g2 = tbl[(q * 4 + 2) * MTBL + ivn.z];
            g3 = tbl[(q * 4 + 3) * MTBL + ivn.w];
        }

#pragma unroll
        for (int t = 0; t < 4; ++t) {
            uint2 pk;
            pk.x = pack2bf(fmaxf(acc[t][0], 0.f), fmaxf(acc[t][1], 0.f));
            pk.y = pack2bf(fmaxf(acc[t][2], 0.f), fmaxf(acc[t][3], 0.f));
            *(uint2*)(hrow + t * 16 + q * 4) = pk;
        }
        Bh0 = *(const short8*)(hrow + q * 8);
        Bh1 = *(const short8*)(hrow + 32 + q * 8);

#pragma unroll
        for (int t = 0; t < 4; ++t) {
            acc[t] = __builtin_amdgcn_mfma_f32_16x16x32_bf16(A3[t][0], Bh0, C3[t], 0, 0, 0);
            acc[t] = __builtin_amdgcn_mfma_f32_16x16x32_bf16(A3[t][1], Bh1, acc[t], 0, 0, 0);
        }

#pragma unroll
        for (int t = 0; t < 4; ++t) {
            uint2 pk;
            pk.x = pack2bf(fmaxf(acc[t][0], 0.f), fmaxf(acc[t][1], 0.f));
            pk.y = pack2bf(fmaxf(acc[t][2], 0.f), fmaxf(acc[t][3], 0.f));
            *(uint2*)(hrow + t * 16 + q * 4) = pk;
        }
        Bh0 = *(const short8*)(hrow + q * 8);
        Bh1 = *(const short8*)(hrow + 32 + q * 8);

        floatx4 o;
        o = __builtin_amdgcn_mfma_f32_16x16x32_bf16(A4[0], Bh0, C4, 0, 0, 0);
        o = __builtin_amdgcn_mfma_f32_16x16x32_bf16(A4[1], Bh1, o, 0, 0, 0);

        if (q == 0) {
            const int pn = pbase + m;
            out[pn * 3 + 0] = o[0];
            out[pn * 3 + 1] = o[1];
            out[pn * 3 + 2] = o[2];
        }
    }
}

extern "C" void kernel_launch(void* const* d_in, const int* in_sizes, int n_in,
                              void* d_out, int out_size, void* d_ws, size_t ws_size,
                              hipStream_t stream) {
    const int*   idx    = (const int*)d_in[0];
    const float* tables = (const float*)d_in[1];
    const float* W1 = (const float*)d_in[2];
    const float* b1 = (const float*)d_in[3];
    const float* W2 = (const float*)d_in[4];
    const float* b2 = (const float*)d_in[5];
    const float* W3 = (const float*)d_in[6];
    const float* b3 = (const float*)d_in[7];
    const float* W4 = (const float*)d_in[8];
    const float* b4 = (const float*)d_in[9];
    float* out = (float*)d_out;

    const int N = in_sizes[0] / 16;            // points (2,097,152)
    const int total_tiles = N / 16;

    const size_t idxT_bytes = (size_t)16 * N * 4;           // 128 MiB
    const size_t xU_bytes   = (size_t)16 * N * 4;           // 128 MiB
    const size_t tblC_bytes = (size_t)16 * MTBL * 4;        // 32 MiB
    const size_t need = idxT_bytes + xU_bytes + tblC_bytes;

    if (ws_size >= need) {
        int*          idxT = (int*)d_ws;
        unsigned int* xU   = (unsigned int*)((char*)d_ws + idxT_bytes);
        unsigned int* tblC = (unsigned int*)((char*)d_ws + idxT_bytes + xU_bytes);

        // P: fused transpose + compress (plain loads, NT stores)
        const int tblocks = N / 1024;
        const int cblocks = (16 * MTBL) / 1024;
        ngp_prep<<<tblocks + cblocks, 256, 0, stream>>>(
            idx, idxT, (const floatx4*)tables, tblC, N);
        // B: both gather phases in one launch (phase = bit 11), coalesced tiling
        const int iters = (N >> 8) >> 11;   // 4
        ngp_gather<<<4096, 256, 0, stream>>>(idxT, tblC, xU, N, iters);
        // C: MFMA MLP (lane-local transitions, 4-tile ILP, 24 KB LDS)
        const int blocks = 2048;
        const int tiles_per_wave = total_tiles / (blocks * 4);   // 16
        ngp_mlp<<<blocks, 256, 0, stream>>>(xU, W1, b1, W2, b2, W3, b3, W4, b4,
                                            out, N, tiles_per_wave);
    } else {
        const int blocks = 2048;
        const int tiles_per_wave = total_tiles / (blocks * 4);
        ngp_fused<<<blocks, 256, 0, stream>>>(idx, tables, W1, b1, W2, b2, W3, b3,
                                              W4, b4, out, tiles_per_wave);
    }
}

// Round 10
// 537.614 us; speedup vs baseline: 1.4134x; 1.0067x over previous
//
#include <hip/hip_runtime.h>
#include <hip/hip_bf16.h>

typedef __attribute__((ext_vector_type(8))) short short8;
typedef __attribute__((ext_vector_type(4))) float floatx4;
typedef __attribute__((ext_vector_type(4))) int int4v;
typedef __attribute__((ext_vector_type(4))) unsigned int uint4v;

#define MTBL 524288
#define HSTRIDE 72   // fallback kernel only

union U4S8 { uint4v u; short8 s; };

// fp32 -> bf16 round-to-nearest (weight preamble / prep kernels)
static __device__ __forceinline__ unsigned int pack2bf(float a, float b) {
    union { float f; unsigned int u; } x, y;
    x.f = a; y.f = b;
    unsigned int lo = (x.u + 0x8000u) >> 16;
    unsigned int hi = (y.u + 0x8000u) & 0xFFFF0000u;
    return lo | hi;
}
static __device__ __forceinline__ short bf1(float a) {
    union { float f; unsigned int u; } x;
    x.f = a;
    return (short)((x.u + 0x8000u) >> 16);
}

// relu + bf16-pack two acc registers into one MFMA B-fragment (8 bf16).
// __float22bfloat162_rn lowers to v_cvt_pk_bf16_f32 (1 instr / 2 values).
static __device__ __forceinline__ short8 relu_pack(floatx4 a, floatx4 b) {
    union { __hip_bfloat162 h2[4]; short8 s; } r;
    r.h2[0] = __float22bfloat162_rn(make_float2(fmaxf(a[0], 0.f), fmaxf(a[1], 0.f)));
    r.h2[1] = __float22bfloat162_rn(make_float2(fmaxf(a[2], 0.f), fmaxf(a[3], 0.f)));
    r.h2[2] = __float22bfloat162_rn(make_float2(fmaxf(b[0], 0.f), fmaxf(b[1], 0.f)));
    r.h2[3] = __float22bfloat162_rn(make_float2(fmaxf(b[2], 0.f), fmaxf(b[3], 0.f)));
    return r.s;
}

// one full MLP chain for a 16-point tile, lane-local transitions.
// Layout trick (R1): A-fragment t covers permuted output columns
//   c_t(p) = 32*(t>>1) + 4*(t&1) + 8*(p>>2) + (p&3)
// so lane (q,m) holds h[32*(t>>1)+4*(t&1)+8q+r] in acc[t][r] and the next
// layer's B-fragment is relu_pack of the SAME lane's accumulators.
static __device__ __forceinline__ floatx4 mlp_chain(
    uint4v cur,
    const short8 (&A1)[4], const short8 (&A2)[4][2], const short8 (&A3)[4][2],
    const short8 (&A4)[2],
    const floatx4 (&C1)[4], const floatx4 (&C2)[4], const floatx4 (&C3)[4],
    floatx4 C4)
{
    U4S8 bx; bx.u = cur;
    const short8 Bx = bx.s;

    floatx4 h[4];
#pragma unroll
    for (int t = 0; t < 4; ++t)
        h[t] = __builtin_amdgcn_mfma_f32_16x16x32_bf16(A1[t], Bx, C1[t], 0, 0, 0);
    short8 B0 = relu_pack(h[0], h[1]);
    short8 B1 = relu_pack(h[2], h[3]);

#pragma unroll
    for (int t = 0; t < 4; ++t) {
        h[t] = __builtin_amdgcn_mfma_f32_16x16x32_bf16(A2[t][0], B0, C2[t], 0, 0, 0);
        h[t] = __builtin_amdgcn_mfma_f32_16x16x32_bf16(A2[t][1], B1, h[t], 0, 0, 0);
    }
    B0 = relu_pack(h[0], h[1]);
    B1 = relu_pack(h[2], h[3]);

#pragma unroll
    for (int t = 0; t < 4; ++t) {
        h[t] = __builtin_amdgcn_mfma_f32_16x16x32_bf16(A3[t][0], B0, C3[t], 0, 0, 0);
        h[t] = __builtin_amdgcn_mfma_f32_16x16x32_bf16(A3[t][1], B1, h[t], 0, 0, 0);
    }
    B0 = relu_pack(h[0], h[1]);
    B1 = relu_pack(h[2], h[3]);

    floatx4 o;
    o = __builtin_amdgcn_mfma_f32_16x16x32_bf16(A4[0], B0, C4, 0, 0, 0);
    o = __builtin_amdgcn_mfma_f32_16x16x32_bf16(A4[1], B1, o, 0, 0, 0);
    return o;
}

// ---------------- Kernel P: fused prep ----------------
// blocks [0, N/512):            LDS transpose idx [N][16] -> idxT [16][N]
// blocks [N/512, +16M/1024):    compress tables fp32 [16*M][2] -> packed bf16
// R9: transpose via LDS so BOTH sides are lane-contiguous.  The old reg
// version had each lane reading 256 contiguous bytes -> every wave load
// instruction scattered over 64 distinct lines (64 L2 req/instr,
// request-bound at ~2.1 TB/s).  LDS [512][17]: pad 16->17 breaks the
// power-of-2 stride (write <=2-way conflict = free; read 8-way on a small
// op count).  All global accesses NT (each line touched exactly once).
__global__ __launch_bounds__(256) void ngp_prep(
    const int* __restrict__ idx, int* __restrict__ idxT,
    const floatx4* __restrict__ tab4, unsigned int* __restrict__ tblC, int N)
{
    __shared__ int lds[512 * 17];            // 34.8 KB -> 4 blocks/CU
    const int tblocks = N >> 9;              // 512 points per block
    const int tid = threadIdx.x;
    if ((int)blockIdx.x < tblocks) {
        const int P = blockIdx.x << 9;
        const int4v* rows = (const int4v*)idx + (size_t)P * 4;   // 4 int4v/point
#pragma unroll
        for (int c = 0; c < 8; ++c) {
            const int g = tid + 256 * c;         // int4v index in block
            int4v v = __builtin_nontemporal_load(rows + g);
            const int lp = g >> 2;               // local point
            const int h0 = (g & 3) * 4;          // head group
#pragma unroll
            for (int j = 0; j < 4; ++j)
                lds[lp * 17 + h0 + j] = v[j];
        }
        __syncthreads();
#pragma unroll
        for (int c = 0; c < 8; ++c) {
            const int g = tid + 256 * c;         // output int4v index
            const int h = g >> 7;                // 128 int4v per head
            const int po4 = g & 127;
            int4v w;
#pragma unroll
            for (int j = 0; j < 4; ++j)
                w[j] = lds[(4 * po4 + j) * 17 + h];
            __builtin_nontemporal_store(
                w, (int4v*)(idxT + (size_t)h * N + P + 4 * po4));
        }
    } else {
        const int t = (blockIdx.x - tblocks) * 256 + tid;
        floatx4 a = __builtin_nontemporal_load(tab4 + (size_t)2 * t);
        floatx4 b = __builtin_nontemporal_load(tab4 + (size_t)2 * t + 1);
        uint4v w;
        w[0] = pack2bf(a[0], a[1]);
        w[1] = pack2bf(a[2], a[3]);
        w[2] = pack2bf(b[0], b[1]);
        w[3] = pack2bf(b[2], b[3]);
        __builtin_nontemporal_store(w, (uint4v*)(tblC + (size_t)4 * t));
    }
}

// ---------------- Kernel B: one-head-per-XCD gather, both phases ----------------
// 4096 blocks: phase = bit 11 of blockIdx; XCD = blk & 7; per-XCD live table
// slice 2 MiB.  idxT/xU accesses are NT (no-allocate) so the table keeps L2.
// Coalesced tiling (R7-verified: WRITE_SIZE 252->128 MB).  At 9.75 req/cyc/XCD
// this kernel sits at the random-L2-bank ceiling (~63% x 16 banks) -- roofline.
__global__ __launch_bounds__(256) void ngp_gather(
    const int* __restrict__ idxT, const unsigned int* __restrict__ tblC,
    unsigned int* __restrict__ xU, int N, int iters)
{
    const int phase = (blockIdx.x >> 11) & 1;
    const int blk   = blockIdx.x & 2047;
    const int h     = ((blk & 7) << 1) | phase;
    const int slot  = blk >> 3;                       // 0..255
    const int* __restrict__ ih = idxT + (size_t)h * N;
    const unsigned int* __restrict__ th = tblC + (size_t)h * MTBL;
    unsigned int* __restrict__ xh = xU + (size_t)h * N;

    int p = slot * (N >> 8) + (threadIdx.x << 2);     // 4 contiguous points/chunk
    int4v iv0 = __builtin_nontemporal_load((const int4v*)(ih + p));
    int4v iv1 = __builtin_nontemporal_load((const int4v*)(ih + p + 1024));
    for (int it = 0; it < iters; ++it) {
        int4v nv0 = iv0, nv1 = iv1;
        if (it + 1 < iters) {
            nv0 = __builtin_nontemporal_load((const int4v*)(ih + p + 2048));
            nv1 = __builtin_nontemporal_load((const int4v*)(ih + p + 3072));
        }
        uint4v w0, w1;
        w0[0] = th[iv0[0]]; w0[1] = th[iv0[1]]; w0[2] = th[iv0[2]]; w0[3] = th[iv0[3]];
        w1[0] = th[iv1[0]]; w1[1] = th[iv1[1]]; w1[2] = th[iv1[2]]; w1[3] = th[iv1[3]];
        __builtin_nontemporal_store(w0, (uint4v*)(xh + p));
        __builtin_nontemporal_store(w1, (uint4v*)(xh + p + 1024));
        iv0 = nv0; iv1 = nv1;
        p += 2048;
    }
}

// ---------------- Kernel C: MFMA MLP on contiguous xU ----------------
// R9: the loop is HBM-LATENCY-bound, not ILP-bound: xU is NT-stored by the
// gather (lives in HBM, ~900 cy) and depth-1 prefetch over one iteration
// (~680 cy of MFMA+pack) doesn't cover it at 25% occupancy.  Fix: 2 chains +
// 4-buffer pipeline -- loads issued THREE iterations ahead (~1000 cy).
// Pipeline buffers named pa*/pb* (R9 compile fail: b1/b2/b3 shadowed the
// bias pointer params).
// launch_bounds (256,2): (256,4) forced VGPR=64 and spilled (R0 post-mortem).
__global__ __launch_bounds__(256, 2) void ngp_mlp(
    const unsigned int* __restrict__ xU,
    const float* __restrict__ W1, const float* __restrict__ b1,
    const float* __restrict__ W2, const float* __restrict__ b2,
    const float* __restrict__ W3, const float* __restrict__ b3,
    const float* __restrict__ W4, const float* __restrict__ b4,
    float* __restrict__ out, int N, int tiles_per_wave)
{
    __shared__ float sW[6144];   // 24 KB, reused across 2 staging stages

    const int tid  = threadIdx.x;
    const int wave = tid >> 6;
    const int lane = tid & 63;
    const int q = lane >> 4;
    const int m = lane & 15;

    int ct[4];
#pragma unroll
    for (int t = 0; t < 4; ++t)
        ct[t] = 32 * (t >> 1) + 4 * (t & 1) + 8 * (m >> 2) + (m & 3);

    short8 A1[4], A2[4][2], A3[4][2], A4[2];
    floatx4 C1[4], C2[4], C3[4], C4;

    // ---- stage A: W1 (2048) + W2 (4096) ----
    for (int i = tid; i < 2048; i += 256) sW[i] = W1[i];
    for (int i = tid; i < 4096; i += 256) sW[2048 + i] = W2[i];
    __syncthreads();
#pragma unroll
    for (int t = 0; t < 4; ++t) {
        short8 a;
#pragma unroll
        for (int j = 0; j < 8; ++j)
            a[j] = bf1(sW[(q * 8 + j) * 64 + ct[t]]);
        A1[t] = a;
    }
#pragma unroll
    for (int t = 0; t < 4; ++t)
#pragma unroll
        for (int c = 0; c < 2; ++c) {
            short8 a;
#pragma unroll
            for (int j = 0; j < 8; ++j)
                a[j] = bf1(sW[2048 + (c * 32 + q * 8 + j) * 64 + ct[t]]);
            A2[t][c] = a;
        }
    __syncthreads();

    // ---- stage B: W3 (4096) + W4 (192) + biases (195) ----
    for (int i = tid; i < 4096; i += 256) sW[i] = W3[i];
    if (tid < 192) sW[4096 + tid] = W4[tid];
    if (tid < 64)       sW[4288 + tid] = b1[tid];
    else if (tid < 128) sW[4288 + tid] = b2[tid - 64];
    else if (tid < 192) sW[4288 + tid] = b3[tid - 128];
    else if (tid < 195) sW[4288 + tid] = b4[tid - 192];
    __syncthreads();
#pragma unroll
    for (int t = 0; t < 4; ++t)
#pragma unroll
        for (int c = 0; c < 2; ++c) {
            short8 a;
#pragma unroll
            for (int j = 0; j < 8; ++j)
                a[j] = bf1(sW[(c * 32 + q * 8 + j) * 64 + ct[t]]);
            A3[t][c] = a;
        }
#pragma unroll
    for (int c = 0; c < 2; ++c) {
        short8 a;
#pragma unroll
        for (int j = 0; j < 8; ++j)
            a[j] = (m < 3) ? bf1(sW[4096 + (c * 32 + q * 8 + j) * 3 + m]) : (short)0;
        A4[c] = a;
    }
#pragma unroll
    for (int t = 0; t < 4; ++t) {
        const int bi = 32 * (t >> 1) + 4 * (t & 1) + 8 * q;   // permuted bias base
#pragma unroll
        for (int r = 0; r < 4; ++r) {
            C1[t][r] = sW[4288 + bi + r];
            C2[t][r] = sW[4288 + 64 + bi + r];
            C3[t][r] = sW[4288 + 128 + bi + r];
        }
    }
#pragma unroll
    for (int r = 0; r < 4; ++r)
        C4[r] = (q == 0 && r < 3) ? sW[4288 + 192 + r] : 0.0f;

    const int gw = blockIdx.x * 4 + wave;
    const int tile0 = gw * tiles_per_wave;
    const int iters = tiles_per_wave >> 1;    // 2 tiles per iteration

    const unsigned int* xr = xU + (size_t)(q * 4) * N + m;

    #define XLD(tile, c) __builtin_nontemporal_load(&xr[(size_t)(c) * N + (tile) * 16])
    #define LDP(A, B, tile) \
        A[0] = XLD(tile, 0);       A[1] = XLD(tile, 1); \
        A[2] = XLD(tile, 2);       A[3] = XLD(tile, 3); \
        B[0] = XLD((tile) + 1, 0); B[1] = XLD((tile) + 1, 1); \
        B[2] = XLD((tile) + 1, 2); B[3] = XLD((tile) + 1, 3);

    // 4-buffer pipeline: buffer j holds tiles (tile0 + 2(k+j), +1)
    uint4v pa0, pb0, pa1, pb1, pa2, pb2, pa3, pb3;
    LDP(pa0, pb0, tile0);
    if (iters > 1) { LDP(pa1, pb1, tile0 + 2); } else { pa1 = pa0; pb1 = pb0; }
    if (iters > 2) { LDP(pa2, pb2, tile0 + 4); } else { pa2 = pa1; pb2 = pb1; }
    pa3 = pa2; pb3 = pb2;

    for (int k = 0; k < iters; ++k) {
        if (k + 3 < iters) { LDP(pa3, pb3, tile0 + 2 * k + 6); }

        floatx4 oA = mlp_chain(pa0, A1, A2, A3, A4, C1, C2, C3, C4);
        floatx4 oB = mlp_chain(pb0, A1, A2, A3, A4, C1, C2, C3, C4);

        if (q == 0) {
            const int pA = (tile0 + 2 * k) * 16 + m;
            __builtin_nontemporal_store(oA[0], out + pA * 3 + 0);
            __builtin_nontemporal_store(oA[1], out + pA * 3 + 1);
            __builtin_nontemporal_store(oA[2], out + pA * 3 + 2);
            const int pB = pA + 16;
            __builtin_nontemporal_store(oB[0], out + pB * 3 + 0);
            __builtin_nontemporal_store(oB[1], out + pB * 3 + 1);
            __builtin_nontemporal_store(oB[2], out + pB * 3 + 2);
        }

        pa0 = pa1; pb0 = pb1;
        pa1 = pa2; pb1 = pb2;
        pa2 = pa3; pb2 = pb3;
    }
    #undef LDP
    #undef XLD
}

// ---------------- Fallback: fused kernel without workspace ----------------
__global__ __launch_bounds__(256, 2) void ngp_fused(
    const int* __restrict__ idx,
    const float* __restrict__ tables,
    const float* __restrict__ W1, const float* __restrict__ b1,
    const float* __restrict__ W2, const float* __restrict__ b2,
    const float* __restrict__ W3, const float* __restrict__ b3,
    const float* __restrict__ W4, const float* __restrict__ b4,
    float* __restrict__ out, int tiles_per_wave)
{
    __shared__ float sW1[2048];
    __shared__ float sW2[4096];
    __shared__ float sW3[4096];
    __shared__ float sW4[192];
    __shared__ float sB[200];
    __shared__ __hip_bfloat16 sH[4][16 * HSTRIDE];

    const int tid = threadIdx.x;
    for (int i = tid; i < 2048; i += 256) sW1[i] = W1[i];
    for (int i = tid; i < 4096; i += 256) sW2[i] = W2[i];
    for (int i = tid; i < 4096; i += 256) sW3[i] = W3[i];
    if (tid < 192) sW4[tid] = W4[tid];
    if (tid < 64)       sB[tid] = b1[tid];
    else if (tid < 128) sB[tid] = b2[tid - 64];
    else if (tid < 192) sB[tid] = b3[tid - 128];
    else if (tid < 195) sB[tid] = b4[tid - 192];
    __syncthreads();

    const int wave = tid >> 6;
    const int lane = tid & 63;
    const int q = lane >> 4;
    const int m = lane & 15;

    short8 A1[4], A2[4][2], A3[4][2], A4[2];
#pragma unroll
    for (int t = 0; t < 4; ++t) {
        short8 a;
#pragma unroll
        for (int j = 0; j < 8; ++j)
            a[j] = bf1(sW1[(q * 8 + j) * 64 + t * 16 + m]);
        A1[t] = a;
    }
#pragma unroll
    for (int t = 0; t < 4; ++t)
#pragma unroll
        for (int c = 0; c < 2; ++c) {
            short8 a, a3;
#pragma unroll
            for (int j = 0; j < 8; ++j) {
                a[j]  = bf1(sW2[(c * 32 + q * 8 + j) * 64 + t * 16 + m]);
                a3[j] = bf1(sW3[(c * 32 + q * 8 + j) * 64 + t * 16 + m]);
            }
            A2[t][c] = a;
            A3[t][c] = a3;
        }
#pragma unroll
    for (int c = 0; c < 2; ++c) {
        short8 a;
#pragma unroll
        for (int j = 0; j < 8; ++j)
            a[j] = (m < 3) ? bf1(sW4[(c * 32 + q * 8 + j) * 3 + m]) : (short)0;
        A4[c] = a;
    }

    floatx4 C1[4], C2[4], C3[4], C4;
#pragma unroll
    for (int t = 0; t < 4; ++t)
#pragma unroll
        for (int r = 0; r < 4; ++r) {
            C1[t][r] = sB[t * 16 + q * 4 + r];
            C2[t][r] = sB[64 + t * 16 + q * 4 + r];
            C3[t][r] = sB[128 + t * 16 + q * 4 + r];
        }
#pragma unroll
    for (int r = 0; r < 4; ++r)
        C4[r] = (q == 0 && r < 3) ? sB[192 + r] : 0.0f;

    __hip_bfloat16* hrow = &sH[wave][m * HSTRIDE];
    const int4*   idx4 = (const int4*)idx;
    const float2* tbl  = (const float2*)tables;

    const int gw = blockIdx.x * 4 + wave;
    const int tile0 = gw * tiles_per_wave;

    int4 iv = idx4[(tile0 * 16 + m) * 4 + q];
    float2 g0 = tbl[(q * 4 + 0) * MTBL + iv.x];
    float2 g1 = tbl[(q * 4 + 1) * MTBL + iv.y];
    float2 g2 = tbl[(q * 4 + 2) * MTBL + iv.z];
    float2 g3 = tbl[(q * 4 + 3) * MTBL + iv.w];

    for (int it = 0; it < tiles_per_wave; ++it) {
        const int pbase = (tile0 + it) * 16;
        const bool more = (it + 1) < tiles_per_wave;

        short8 Bx;
        {
            unsigned int p0 = pack2bf(g0.x, g0.y);
            unsigned int p1 = pack2bf(g1.x, g1.y);
            unsigned int p2 = pack2bf(g2.x, g2.y);
            unsigned int p3 = pack2bf(g3.x, g3.y);
            Bx[0] = (short)(p0 & 0xFFFF); Bx[1] = (short)(p0 >> 16);
            Bx[2] = (short)(p1 & 0xFFFF); Bx[3] = (short)(p1 >> 16);
            Bx[4] = (short)(p2 & 0xFFFF); Bx[5] = (short)(p2 >> 16);
            Bx[6] = (short)(p3 & 0xFFFF); Bx[7] = (short)(p3 >> 16);
        }

        int4 ivn;
        if (more) ivn = idx4[((pbase + 16) + m) * 4 + q];

        floatx4 acc[4];
#pragma unroll
        for (int t = 0; t < 4; ++t)
            acc[t] = __builtin_amdgcn_mfma_f32_16x16x32_bf16(A1[t], Bx, C1[t], 0, 0, 0);

#pragma unroll
        for (int t = 0; t < 4; ++t) {
            uint2 pk;
            pk.x = pack2bf(fmaxf(acc[t][0], 0.f), fmaxf(acc[t][1], 0.f));
            pk.y = pack2bf(fmaxf(acc[t][2], 0.f), fmaxf(acc[t][3], 0.f));
            *(uint2*)(hrow + t * 16 + q * 4) = pk;
        }
        short8 Bh0 = *(const short8*)(hrow + q * 8);
        short8 Bh1 = *(const short8*)(hrow + 32 + q * 8);

#pragma unroll
        for (int t = 0; t < 4; ++t) {
            acc[t] = __builtin_amdgcn_mfma_f32_16x16x32_bf16(A2[t][0], Bh0, C2[t], 0, 0, 0);
            acc[t] = __builtin_amdgcn_mfma_f32_16x16x32_bf16(A2[t][1], Bh1, acc[t], 0, 0, 0);
        }

        if (more) {
            g0 = tbl[(q * 4 + 0) * MTBL + ivn.x];
            g1 = tbl[(q * 4 + 1) * MTBL + ivn.y];
            g2 = tbl[(q * 4 + 2) * MTBL + ivn.z];
            g3 = tbl[(q * 4 + 3) * MTBL + ivn.w];
        }

#pragma unroll
        for (int t = 0; t < 4; ++t) {
            uint2 pk;
            pk.x = pack2bf(fmaxf(acc[t][0], 0.f), fmaxf(acc[t][1], 0.f));
            pk.y = pack2bf(fmaxf(acc[t][2], 0.f), fmaxf(acc[t][3], 0.f));
            *(uint2*)(hrow + t * 16 + q * 4) = pk;
        }
        Bh0 = *(const short8*)(hrow + q * 8);
        Bh1 = *(const short8*)(hrow + 32 + q * 8);

#pragma unroll
        for (int t = 0; t < 4; ++t) {
            acc[t] = __builtin_amdgcn_mfma_f32_16x16x32_bf16(A3[t][0], Bh0, C3[t], 0, 0, 0);
            acc[t] = __builtin_amdgcn_mfma_f32_16x16x32_bf16(A3[t][1], Bh1, acc[t], 0, 0, 0);
        }

#pragma unroll
        for (int t = 0; t < 4; ++t) {
            uint2 pk;
            pk.x = pack2bf(fmaxf(acc[t][0], 0.f), fmaxf(acc[t][1], 0.f));
            pk.y = pack2bf(fmaxf(acc[t][2], 0.f), fmaxf(acc[t][3], 0.f));
            *(uint2*)(hrow + t * 16 + q * 4) = pk;
        }
        Bh0 = *(const short8*)(hrow + q * 8);
        Bh1 = *(const short8*)(hrow + 32 + q * 8);

        floatx4 o;
        o = __builtin_amdgcn_mfma_f32_16x16x32_bf16(A4[0], Bh0, C4, 0, 0, 0);
        o = __builtin_amdgcn_mfma_f32_16x16x32_bf16(A4[1], Bh1, o, 0, 0, 0);

        if (q == 0) {
            const int pn = pbase + m;
            out[pn * 3 + 0] = o[0];
            out[pn * 3 + 1] = o[1];
            out[pn * 3 + 2] = o[2];
        }
    }
}

extern "C" void kernel_launch(void* const* d_in, const int* in_sizes, int n_in,
                              void* d_out, int out_size, void* d_ws, size_t ws_size,
                              hipStream_t stream) {
    const int*   idx    = (const int*)d_in[0];
    const float* tables = (const float*)d_in[1];
    const float* W1 = (const float*)d_in[2];
    const float* b1 = (const float*)d_in[3];
    const float* W2 = (const float*)d_in[4];
    const float* b2 = (const float*)d_in[5];
    const float* W3 = (const float*)d_in[6];
    const float* b3 = (const float*)d_in[7];
    const float* W4 = (const float*)d_in[8];
    const float* b4 = (const float*)d_in[9];
    float* out = (float*)d_out;

    const int N = in_sizes[0] / 16;            // points (2,097,152)
    const int total_tiles = N / 16;

    const size_t idxT_bytes = (size_t)16 * N * 4;           // 128 MiB
    const size_t xU_bytes   = (size_t)16 * N * 4;           // 128 MiB
    const size_t tblC_bytes = (size_t)16 * MTBL * 4;        // 32 MiB
    const size_t need = idxT_bytes + xU_bytes + tblC_bytes;

    if (ws_size >= need) {
        int*          idxT = (int*)d_ws;
        unsigned int* xU   = (unsigned int*)((char*)d_ws + idxT_bytes);
        unsigned int* tblC = (unsigned int*)((char*)d_ws + idxT_bytes + xU_bytes);

        // P: fused LDS-transpose + compress (coalesced both sides, NT)
        const int tblocks = N / 512;
        const int cblocks = (16 * MTBL) / 1024;
        ngp_prep<<<tblocks + cblocks, 256, 0, stream>>>(
            idx, idxT, (const floatx4*)tables, tblC, N);
        // B: both gather phases in one launch (phase = bit 11), coalesced tiling
        const int iters = (N >> 8) >> 11;   // 4
        ngp_gather<<<4096, 256, 0, stream>>>(idxT, tblC, xU, N, iters);
        // C: MFMA MLP (lane-local transitions, 2-chain + 4-buffer pipeline)
        const int blocks = 2048;
        const int tiles_per_wave = total_tiles / (blocks * 4);   // 16
        ngp_mlp<<<blocks, 256, 0, stream>>>(xU, W1, b1, W2, b2, W3, b3, W4, b4,
                                            out, N, tiles_per_wave);
    } else {
        const int blocks = 2048;
        const int tiles_per_wave = total_tiles / (blocks * 4);
        ngp_fused<<<blocks, 256, 0, stream>>>(idx, tables, W1, b1, W2, b2, W3, b3,
                                              W4, b4, out, tiles_per_wave);
    }
}